// Round 1
// baseline (654.420 us; speedup 1.0000x reference)
//
#include <hip/hip_runtime.h>

#define N_NODES 50000
#define N_EDGES 600000
#define D 128

// ---------------------------------------------------------------------------
// deg[i] = 1.0 (self loop) ; then += ew over edges with dst==i
// ---------------------------------------------------------------------------
__global__ void init_deg_kernel(float* __restrict__ deg) {
    int i = blockIdx.x * 256 + threadIdx.x;
    if (i < N_NODES) deg[i] = 1.0f;
}

__global__ void deg_accum_kernel(const int* __restrict__ dst,
                                 const float* __restrict__ ew,
                                 float* __restrict__ deg) {
    int e = blockIdx.x * 256 + threadIdx.x;
    if (e < N_EDGES) atomicAdd(&deg[dst[e]], ew[e]);
}

__global__ void dinv_kernel(const float* __restrict__ deg, float* __restrict__ dinv) {
    int i = blockIdx.x * 256 + threadIdx.x;
    if (i < N_NODES) {
        float d = deg[i];
        dinv[i] = (d > 0.0f) ? rsqrtf(d) : 0.0f;
    }
}

// ---------------------------------------------------------------------------
// h = x @ W   (f32, vector ALU; no fp32 MFMA on CDNA4)
// Block = 256 threads -> 2 rows x 128 cols. x rows staged in LDS; W reads are
// coalesced (lane i -> col i) and L2-resident (64 KB, reused by all blocks).
// ---------------------------------------------------------------------------
__global__ void gemm_xw_kernel(const float* __restrict__ x,
                               const float* __restrict__ W,
                               float* __restrict__ h) {
    __shared__ float xs[2][D];
    int lr  = threadIdx.x >> 7;   // 0..1 local row
    int col = threadIdx.x & 127;
    int row = blockIdx.x * 2 + lr;
    if (row < N_NODES) {
        xs[lr][col] = x[(size_t)row * D + col];
    }
    __syncthreads();
    if (row >= N_NODES) return;
    float acc = 0.0f;
#pragma unroll 8
    for (int k = 0; k < D; ++k) {
        acc = fmaf(xs[lr][k], W[k * D + col], acc);
    }
    h[(size_t)row * D + col] = acc;
}

// ---------------------------------------------------------------------------
// Edge scatter: acc[dst] += h[src] * (dinv[src]*ew*dinv[dst])
// One 64-lane wave group per edge; each lane handles 2 features (float2 load,
// 2 scalar f32 atomics). Block = 256 threads = 4 edges.
// ---------------------------------------------------------------------------
__global__ void scatter_kernel(const int* __restrict__ src,
                               const int* __restrict__ dst,
                               const float* __restrict__ ew,
                               const float* __restrict__ dinv,
                               const float* __restrict__ h,
                               float* __restrict__ acc) {
    int e = blockIdx.x * 4 + (threadIdx.x >> 6);
    if (e >= N_EDGES) return;
    int lane = threadIdx.x & 63;
    int s = src[e];
    int d = dst[e];
    float w = ew[e] * dinv[s] * dinv[d];
    float2 v = ((const float2*)(h + (size_t)s * D))[lane];
    float* ap = acc + (size_t)d * D + lane * 2;
    atomicAdd(ap,     v.x * w);
    atomicAdd(ap + 1, v.y * w);
}

// ---------------------------------------------------------------------------
// Finalize: out = relu(acc + h[i]*dinv[i]^2 (self loop) + b)
// ---------------------------------------------------------------------------
__global__ void finalize_kernel(const float* __restrict__ h,
                                const float* __restrict__ dinv,
                                const float* __restrict__ b,
                                float* __restrict__ out) {
    int i = blockIdx.x * 256 + threadIdx.x;
    if (i >= N_NODES * D) return;
    int node = i >> 7;
    int col  = i & 127;
    float di = dinv[node];
    float v = out[i] + h[i] * di * di + b[col];
    out[i] = fmaxf(v, 0.0f);
}

extern "C" void kernel_launch(void* const* d_in, const int* in_sizes, int n_in,
                              void* d_out, int out_size, void* d_ws, size_t ws_size,
                              hipStream_t stream) {
    const float* x    = (const float*)d_in[0];
    const int*   ei   = (const int*)d_in[1];   // [2, E] flat: src then dst
    const float* ew   = (const float*)d_in[2];
    const float* W    = (const float*)d_in[3];
    const float* b    = (const float*)d_in[4];
    float*       out  = (float*)d_out;

    const int* src = ei;
    const int* dst = ei + N_EDGES;

    // workspace layout
    float* h    = (float*)d_ws;            // N_NODES*D floats (25.6 MB)
    float* deg  = h + (size_t)N_NODES * D; // N_NODES floats
    float* dinv = deg + N_NODES;           // N_NODES floats

    // zero the output accumulator (harness poisons once, never re-poisons)
    hipMemsetAsync(d_out, 0, (size_t)out_size * sizeof(float), stream);

    init_deg_kernel<<<(N_NODES + 255) / 256, 256, 0, stream>>>(deg);
    deg_accum_kernel<<<(N_EDGES + 255) / 256, 256, 0, stream>>>(dst, ew, deg);
    dinv_kernel<<<(N_NODES + 255) / 256, 256, 0, stream>>>(deg, dinv);

    gemm_xw_kernel<<<(N_NODES + 1) / 2, 256, 0, stream>>>(x, W, h);

    scatter_kernel<<<(N_EDGES + 3) / 4, 256, 0, stream>>>(src, dst, ew, dinv, h, out);

    finalize_kernel<<<(N_NODES * D + 255) / 256, 256, 0, stream>>>(h, dinv, b, out);
}

// Round 2
// 256.216 us; speedup vs baseline: 2.5542x; 2.5542x over previous
//
#include <hip/hip_runtime.h>

#define N_NODES 50000
#define N_EDGES 600000
#define D 128
#define SCAN_B 256
#define NB ((N_NODES + SCAN_B - 1) / SCAN_B)   // 196 blocks

// ---------------------------------------------------------------------------
// deg[i] = 1.0 (self loop), cnt[i] = 0
// ---------------------------------------------------------------------------
__global__ void init_kernel(float* __restrict__ deg, int* __restrict__ cnt) {
    int i = blockIdx.x * 256 + threadIdx.x;
    if (i < N_NODES) { deg[i] = 1.0f; cnt[i] = 0; }
}

// deg[dst] += ew ; cnt[dst] += 1   (cheap atomics on 50K counters)
__global__ void deg_cnt_kernel(const int* __restrict__ dst,
                               const float* __restrict__ ew,
                               float* __restrict__ deg,
                               int* __restrict__ cnt) {
    int e = blockIdx.x * 256 + threadIdx.x;
    if (e < N_EDGES) {
        int d = dst[e];
        atomicAdd(&deg[d], ew[e]);
        atomicAdd(&cnt[d], 1);
    }
}

__global__ void dinv_kernel(const float* __restrict__ deg, float* __restrict__ dinv) {
    int i = blockIdx.x * 256 + threadIdx.x;
    if (i < N_NODES) {
        float d = deg[i];
        dinv[i] = (d > 0.0f) ? rsqrtf(d) : 0.0f;
    }
}

// ---------------------------------------------------------------------------
// Exclusive scan of cnt[0..N) -> off[], hierarchical (3 tiny kernels)
// ---------------------------------------------------------------------------
__global__ void scan1_kernel(int* __restrict__ cnt, int* __restrict__ blockSums) {
    __shared__ int s[SCAN_B];
    int t = threadIdx.x;
    int i = blockIdx.x * SCAN_B + t;
    int v = (i < N_NODES) ? cnt[i] : 0;
    s[t] = v;
    __syncthreads();
    for (int o = 1; o < SCAN_B; o <<= 1) {
        int x = (t >= o) ? s[t - o] : 0;
        __syncthreads();
        s[t] += x;
        __syncthreads();
    }
    if (i < N_NODES) cnt[i] = s[t] - v;           // block-local exclusive
    if (t == SCAN_B - 1) blockSums[blockIdx.x] = s[t];
}

__global__ void scan2_kernel(int* __restrict__ blockSums) {
    __shared__ int s[SCAN_B];
    int t = threadIdx.x;
    int v = (t < NB) ? blockSums[t] : 0;
    s[t] = v;
    __syncthreads();
    for (int o = 1; o < SCAN_B; o <<= 1) {
        int x = (t >= o) ? s[t - o] : 0;
        __syncthreads();
        s[t] += x;
        __syncthreads();
    }
    if (t < NB) blockSums[t] = s[t] - v;          // exclusive over block sums
}

// off[i] = exclusive prefix; cnt[i] becomes the fill cursor (same value)
__global__ void scan3_kernel(int* __restrict__ cnt, const int* __restrict__ blockSums,
                             int* __restrict__ off) {
    int i = blockIdx.x * SCAN_B + threadIdx.x;
    if (i < N_NODES) {
        int o = cnt[i] + blockSums[blockIdx.x];
        off[i] = o;
        cnt[i] = o;                                // reuse as cursor
    }
    if (i == 0) off[N_NODES] = N_EDGES;
}

// ---------------------------------------------------------------------------
// Fill dst-sorted edge arrays: srcs_s[pos], w_s[pos] = ew*dinv[s]*dinv[d]
// ---------------------------------------------------------------------------
__global__ void fill_kernel(const int* __restrict__ src, const int* __restrict__ dst,
                            const float* __restrict__ ew, const float* __restrict__ dinv,
                            int* __restrict__ cursor,
                            int* __restrict__ srcs_s, float* __restrict__ w_s) {
    int e = blockIdx.x * 256 + threadIdx.x;
    if (e >= N_EDGES) return;
    int s = src[e];
    int d = dst[e];
    int pos = atomicAdd(&cursor[d], 1);
    srcs_s[pos] = s;
    w_s[pos] = ew[e] * dinv[s] * dinv[d];
}

// ---------------------------------------------------------------------------
// h = x @ W   (f32 vector ALU)
// ---------------------------------------------------------------------------
__global__ void gemm_xw_kernel(const float* __restrict__ x,
                               const float* __restrict__ W,
                               float* __restrict__ h) {
    __shared__ float xs[2][D];
    int lr  = threadIdx.x >> 7;
    int col = threadIdx.x & 127;
    int row = blockIdx.x * 2 + lr;
    if (row < N_NODES) xs[lr][col] = x[(size_t)row * D + col];
    __syncthreads();
    if (row >= N_NODES) return;
    float acc = 0.0f;
#pragma unroll 8
    for (int k = 0; k < D; ++k) acc = fmaf(xs[lr][k], W[k * D + col], acc);
    h[(size_t)row * D + col] = acc;
}

// ---------------------------------------------------------------------------
// Gather: one wave per node. out = relu(sum_e h[src_e]*w_e + h[node]*dinv^2 + b)
// Edge metadata loaded 64-wide, broadcast via shfl; h rows read as float2.
// ---------------------------------------------------------------------------
__global__ __launch_bounds__(256) void gather_kernel(
        const int* __restrict__ off, const int* __restrict__ srcs_s,
        const float* __restrict__ w_s, const float* __restrict__ dinv,
        const float* __restrict__ h, const float* __restrict__ b,
        float* __restrict__ out) {
    int node = blockIdx.x * 4 + (threadIdx.x >> 6);
    if (node >= N_NODES) return;
    int lane = threadIdx.x & 63;

    int begin = off[node];
    int end   = off[node + 1];
    float dd  = dinv[node];

    float2 hv = ((const float2*)(h + (size_t)node * D))[lane];
    float sw = dd * dd;
    float accx = hv.x * sw;
    float accy = hv.y * sw;

    for (int j0 = begin; j0 < end; j0 += 64) {
        int n = end - j0;
        if (n > 64) n = 64;
        int s = 0;
        float w = 0.0f;
        if (lane < n) {
            s = srcs_s[j0 + lane];
            w = w_s[j0 + lane];
        }
        for (int t = 0; t < n; ++t) {
            int   ss = __shfl(s, t);
            float ww = __shfl(w, t);
            float2 v = ((const float2*)(h + (size_t)ss * D))[lane];
            accx = fmaf(v.x, ww, accx);
            accy = fmaf(v.y, ww, accy);
        }
    }
    float2 bb = ((const float2*)b)[lane];
    int o = node * D + lane * 2;
    out[o]     = fmaxf(accx + bb.x, 0.0f);
    out[o + 1] = fmaxf(accy + bb.y, 0.0f);
}

// ---------------------------------------------------------------------------
// Fallback path (small ws): atomic scatter (round-0 version)
// ---------------------------------------------------------------------------
__global__ void scatter_kernel(const int* __restrict__ src, const int* __restrict__ dst,
                               const float* __restrict__ ew, const float* __restrict__ dinv,
                               const float* __restrict__ h, float* __restrict__ acc) {
    int e = blockIdx.x * 4 + (threadIdx.x >> 6);
    if (e >= N_EDGES) return;
    int lane = threadIdx.x & 63;
    int s = src[e];
    int d = dst[e];
    float w = ew[e] * dinv[s] * dinv[d];
    float2 v = ((const float2*)(h + (size_t)s * D))[lane];
    float* ap = acc + (size_t)d * D + lane * 2;
    atomicAdd(ap,     v.x * w);
    atomicAdd(ap + 1, v.y * w);
}

__global__ void finalize_kernel(const float* __restrict__ h, const float* __restrict__ dinv,
                                const float* __restrict__ b, float* __restrict__ out) {
    int i = blockIdx.x * 256 + threadIdx.x;
    if (i >= N_NODES * D) return;
    int node = i >> 7;
    int col  = i & 127;
    float di = dinv[node];
    float v = out[i] + h[i] * di * di + b[col];
    out[i] = fmaxf(v, 0.0f);
}

extern "C" void kernel_launch(void* const* d_in, const int* in_sizes, int n_in,
                              void* d_out, int out_size, void* d_ws, size_t ws_size,
                              hipStream_t stream) {
    const float* x  = (const float*)d_in[0];
    const int*   ei = (const int*)d_in[1];   // [2, E]: src row then dst row
    const float* ew = (const float*)d_in[2];
    const float* W  = (const float*)d_in[3];
    const float* b  = (const float*)d_in[4];
    float*       out = (float*)d_out;

    const int* src = ei;
    const int* dst = ei + N_EDGES;

    // workspace layout (elements, all 4 B)
    float* h         = (float*)d_ws;                         // N*D
    float* deg       = h + (size_t)N_NODES * D;              // N
    float* dinv      = deg + N_NODES;                        // N
    int*   cnt       = (int*)(dinv + N_NODES);               // N (becomes cursor)
    int*   off       = cnt + N_NODES;                        // N+1
    int*   blockSums = off + (N_NODES + 1);                  // SCAN_B
    int*   srcs_s    = blockSums + SCAN_B;                   // E
    float* w_s       = (float*)(srcs_s + N_EDGES);           // E
    size_t need = ((size_t)(w_s + N_EDGES) - (size_t)d_ws);

    if (ws_size >= need) {
        // ---------------- CSR gather path ----------------
        init_kernel<<<(N_NODES + 255) / 256, 256, 0, stream>>>(deg, cnt);
        deg_cnt_kernel<<<(N_EDGES + 255) / 256, 256, 0, stream>>>(dst, ew, deg, cnt);
        dinv_kernel<<<(N_NODES + 255) / 256, 256, 0, stream>>>(deg, dinv);

        scan1_kernel<<<NB, SCAN_B, 0, stream>>>(cnt, blockSums);
        scan2_kernel<<<1, SCAN_B, 0, stream>>>(blockSums);
        scan3_kernel<<<NB, SCAN_B, 0, stream>>>(cnt, blockSums, off);

        fill_kernel<<<(N_EDGES + 255) / 256, 256, 0, stream>>>(src, dst, ew, dinv,
                                                               cnt, srcs_s, w_s);

        gemm_xw_kernel<<<(N_NODES + 1) / 2, 256, 0, stream>>>(x, W, h);

        gather_kernel<<<(N_NODES + 3) / 4, 256, 0, stream>>>(off, srcs_s, w_s, dinv,
                                                             h, b, out);
    } else {
        // ---------------- fallback: atomic scatter ----------------
        hipMemsetAsync(d_out, 0, (size_t)out_size * sizeof(float), stream);
        init_kernel<<<(N_NODES + 255) / 256, 256, 0, stream>>>(deg, cnt);
        deg_cnt_kernel<<<(N_EDGES + 255) / 256, 256, 0, stream>>>(dst, ew, deg, cnt);
        dinv_kernel<<<(N_NODES + 255) / 256, 256, 0, stream>>>(deg, dinv);
        gemm_xw_kernel<<<(N_NODES + 1) / 2, 256, 0, stream>>>(x, W, h);
        scatter_kernel<<<(N_EDGES + 3) / 4, 256, 0, stream>>>(src, dst, ew, dinv, h, out);
        finalize_kernel<<<(N_NODES * D + 255) / 256, 256, 0, stream>>>(h, dinv, b, out);
    }
}

// Round 3
// 182.116 us; speedup vs baseline: 3.5934x; 1.4069x over previous
//
#include <hip/hip_runtime.h>

#define N_NODES 50000
#define N_EDGES 600000
#define D 128
#define SCAN_B 256
#define NB ((N_NODES + SCAN_B - 1) / SCAN_B)   // 196 blocks

typedef __attribute__((ext_vector_type(8))) short short8;
typedef __attribute__((ext_vector_type(4))) float f32x4;

__device__ __forceinline__ ushort f2bf(float f) {
    unsigned u = __float_as_uint(f);
    unsigned r = (u + 0x7FFFu + ((u >> 16) & 1u)) >> 16;   // RNE
    return (ushort)r;
}
__device__ __forceinline__ float bf2f(ushort h) {
    return __uint_as_float(((unsigned)h) << 16);
}

// ---------------------------------------------------------------------------
// deg/cnt init + accumulate + dinv
// ---------------------------------------------------------------------------
__global__ void init_kernel(float* __restrict__ deg, int* __restrict__ cnt) {
    int i = blockIdx.x * 256 + threadIdx.x;
    if (i < N_NODES) { deg[i] = 1.0f; cnt[i] = 0; }
}

__global__ void deg_cnt_kernel(const int* __restrict__ dst,
                               const float* __restrict__ ew,
                               float* __restrict__ deg,
                               int* __restrict__ cnt) {
    int e = blockIdx.x * 256 + threadIdx.x;
    if (e < N_EDGES) {
        int d = dst[e];
        atomicAdd(&deg[d], ew[e]);
        atomicAdd(&cnt[d], 1);
    }
}

__global__ void dinv_kernel(const float* __restrict__ deg, float* __restrict__ dinv) {
    int i = blockIdx.x * 256 + threadIdx.x;
    if (i < N_NODES) {
        float d = deg[i];
        dinv[i] = (d > 0.0f) ? rsqrtf(d) : 0.0f;
    }
}

// ---------------------------------------------------------------------------
// Exclusive scan of cnt -> off (3 tiny kernels)
// ---------------------------------------------------------------------------
__global__ void scan1_kernel(int* __restrict__ cnt, int* __restrict__ blockSums) {
    __shared__ int s[SCAN_B];
    int t = threadIdx.x;
    int i = blockIdx.x * SCAN_B + t;
    int v = (i < N_NODES) ? cnt[i] : 0;
    s[t] = v;
    __syncthreads();
    for (int o = 1; o < SCAN_B; o <<= 1) {
        int x = (t >= o) ? s[t - o] : 0;
        __syncthreads();
        s[t] += x;
        __syncthreads();
    }
    if (i < N_NODES) cnt[i] = s[t] - v;
    if (t == SCAN_B - 1) blockSums[blockIdx.x] = s[t];
}

__global__ void scan2_kernel(int* __restrict__ blockSums) {
    __shared__ int s[SCAN_B];
    int t = threadIdx.x;
    int v = (t < NB) ? blockSums[t] : 0;
    s[t] = v;
    __syncthreads();
    for (int o = 1; o < SCAN_B; o <<= 1) {
        int x = (t >= o) ? s[t - o] : 0;
        __syncthreads();
        s[t] += x;
        __syncthreads();
    }
    if (t < NB) blockSums[t] = s[t] - v;
}

__global__ void scan3_kernel(int* __restrict__ cnt, const int* __restrict__ blockSums,
                             int* __restrict__ off) {
    int i = blockIdx.x * SCAN_B + threadIdx.x;
    if (i < N_NODES) {
        int o = cnt[i] + blockSums[blockIdx.x];
        off[i] = o;
        cnt[i] = o;
    }
    if (i == 0) off[N_NODES] = N_EDGES;
}

// ---------------------------------------------------------------------------
// Fill dst-sorted edge arrays
// ---------------------------------------------------------------------------
__global__ void fill_kernel(const int* __restrict__ src, const int* __restrict__ dst,
                            const float* __restrict__ ew, const float* __restrict__ dinv,
                            int* __restrict__ cursor,
                            int* __restrict__ srcs_s, float* __restrict__ w_s) {
    int e = blockIdx.x * 256 + threadIdx.x;
    if (e >= N_EDGES) return;
    int s = src[e];
    int d = dst[e];
    int pos = atomicAdd(&cursor[d], 1);
    srcs_s[pos] = s;
    w_s[pos] = ew[e] * dinv[s] * dinv[d];
}

// ---------------------------------------------------------------------------
// W fragment precompute: Bfrag[ct][ks][lane][j] (hi and lo bf16 split).
// B lane layout for mfma_f32_16x16x32_bf16: col = lane&15, k = 8*(lane>>4)+j.
// ---------------------------------------------------------------------------
__global__ void wfrag_kernel(const float* __restrict__ W,
                             ushort* __restrict__ wfh, ushort* __restrict__ wfl) {
    int t = blockIdx.x * 256 + threadIdx.x;    // 2048 threads total
    int lane = t & 63;
    int ks   = (t >> 6) & 3;
    int ct   = t >> 8;
    int n  = ct * 16 + (lane & 15);
    int k0 = ks * 32 + (lane >> 4) * 8;
    ushort hv[8], lv[8];
#pragma unroll
    for (int j = 0; j < 8; ++j) {
        float v = W[(k0 + j) * D + n];
        ushort hh = f2bf(v);
        hv[j] = hh;
        lv[j] = f2bf(v - bf2f(hh));
    }
    size_t base = (((size_t)ct * 4 + ks) * 64 + lane) * 8;
#pragma unroll
    for (int j = 0; j < 8; ++j) { wfh[base + j] = hv[j]; wfl[base + j] = lv[j]; }
}

// ---------------------------------------------------------------------------
// h = x @ W via bf16 MFMA with hi/lo split (f32-class accuracy).
// Block: 256 threads = 4 waves, 64 rows. x-tile staged in LDS as bf16 hi/lo
// with XOR swizzle (byte ^= (row&7)<<4) to kill stride-256B bank conflicts.
// ---------------------------------------------------------------------------
__global__ __launch_bounds__(256) void gemm_mfma_kernel(
        const float* __restrict__ x,
        const ushort* __restrict__ wfh, const ushort* __restrict__ wfl,
        float* __restrict__ h) {
    __shared__ __attribute__((aligned(16))) ushort xh[64 * 128];
    __shared__ __attribute__((aligned(16))) ushort xl[64 * 128];

    int t  = threadIdx.x;
    int r0 = blockIdx.x * 64;

    // ---- stage: 8 passes x 8 rows; 32 threads/row each loading float4 ----
#pragma unroll
    for (int p = 0; p < 8; ++p) {
        int row  = p * 8 + (t >> 5);
        int g    = t & 31;                  // which float4 chunk of the row
        int grow = r0 + row;
        float4 v = make_float4(0.f, 0.f, 0.f, 0.f);
        if (grow < N_NODES) v = ((const float4*)(x + (size_t)grow * D))[g];
        ushort4 hi, lo;
        hi.x = f2bf(v.x); lo.x = f2bf(v.x - bf2f(hi.x));
        hi.y = f2bf(v.y); lo.y = f2bf(v.y - bf2f(hi.y));
        hi.z = f2bf(v.z); lo.z = f2bf(v.z - bf2f(hi.z));
        hi.w = f2bf(v.w); lo.w = f2bf(v.w - bf2f(hi.w));
        int bo = (row * 256 + g * 8) ^ ((row & 7) << 4);
        *(ushort4*)((char*)xh + bo) = hi;
        *(ushort4*)((char*)xl + bo) = lo;
    }
    __syncthreads();

    int w  = t >> 6;          // wave id -> rows w*16..w*16+15
    int l  = t & 63;
    int m  = l & 15;          // M-row within tile / N-col for B
    int gq = l >> 4;          // k-group

    f32x4 acc[8];
#pragma unroll
    for (int ct = 0; ct < 8; ++ct) acc[ct] = (f32x4){0.f, 0.f, 0.f, 0.f};

#pragma unroll
    for (int ks = 0; ks < 4; ++ks) {
        int row = w * 16 + m;
        int bo  = (row * 256 + gq * 16 + ks * 64) ^ ((row & 7) << 4);
        short8 ah = *(const short8*)((const char*)xh + bo);
        short8 al = *(const short8*)((const char*)xl + bo);
#pragma unroll
        for (int ct = 0; ct < 8; ++ct) {
            size_t fb = (((size_t)ct * 4 + ks) * 64 + l) * 8;
            short8 bh = *(const short8*)(wfh + fb);
            short8 bl = *(const short8*)(wfl + fb);
            acc[ct] = __builtin_amdgcn_mfma_f32_16x16x32_bf16(ah, bh, acc[ct], 0, 0, 0);
            acc[ct] = __builtin_amdgcn_mfma_f32_16x16x32_bf16(al, bh, acc[ct], 0, 0, 0);
            acc[ct] = __builtin_amdgcn_mfma_f32_16x16x32_bf16(ah, bl, acc[ct], 0, 0, 0);
        }
    }

    // ---- C write: row = (l>>4)*4 + reg, col = ct*16 + (l&15) ----
    int orow0 = r0 + w * 16 + gq * 4;
#pragma unroll
    for (int ct = 0; ct < 8; ++ct) {
#pragma unroll
        for (int r = 0; r < 4; ++r) {
            int row = orow0 + r;
            if (row < N_NODES) h[(size_t)row * D + ct * 16 + m] = acc[ct][r];
        }
    }
}

// ---------------------------------------------------------------------------
// Fallback f32 GEMM (small-ws path only)
// ---------------------------------------------------------------------------
__global__ void gemm_xw_kernel(const float* __restrict__ x,
                               const float* __restrict__ W,
                               float* __restrict__ h) {
    __shared__ float xs[2][D];
    int lr  = threadIdx.x >> 7;
    int col = threadIdx.x & 127;
    int row = blockIdx.x * 2 + lr;
    if (row < N_NODES) xs[lr][col] = x[(size_t)row * D + col];
    __syncthreads();
    if (row >= N_NODES) return;
    float acc = 0.0f;
#pragma unroll 8
    for (int k = 0; k < D; ++k) acc = fmaf(xs[lr][k], W[k * D + col], acc);
    h[(size_t)row * D + col] = acc;
}

// ---------------------------------------------------------------------------
// Gather: one wave per node.
// ---------------------------------------------------------------------------
__global__ __launch_bounds__(256) void gather_kernel(
        const int* __restrict__ off, const int* __restrict__ srcs_s,
        const float* __restrict__ w_s, const float* __restrict__ dinv,
        const float* __restrict__ h, const float* __restrict__ b,
        float* __restrict__ out) {
    int node = blockIdx.x * 4 + (threadIdx.x >> 6);
    if (node >= N_NODES) return;
    int lane = threadIdx.x & 63;

    int begin = off[node];
    int end   = off[node + 1];
    float dd  = dinv[node];

    float2 hv = ((const float2*)(h + (size_t)node * D))[lane];
    float sw = dd * dd;
    float accx = hv.x * sw;
    float accy = hv.y * sw;

    for (int j0 = begin; j0 < end; j0 += 64) {
        int n = end - j0;
        if (n > 64) n = 64;
        int s = 0;
        float w = 0.0f;
        if (lane < n) {
            s = srcs_s[j0 + lane];
            w = w_s[j0 + lane];
        }
        for (int t = 0; t < n; ++t) {
            int   ss = __shfl(s, t);
            float ww = __shfl(w, t);
            float2 v = ((const float2*)(h + (size_t)ss * D))[lane];
            accx = fmaf(v.x, ww, accx);
            accy = fmaf(v.y, ww, accy);
        }
    }
    float2 bb = ((const float2*)b)[lane];
    int o = node * D + lane * 2;
    out[o]     = fmaxf(accx + bb.x, 0.0f);
    out[o + 1] = fmaxf(accy + bb.y, 0.0f);
}

// ---------------------------------------------------------------------------
// Fallback path kernels (atomic scatter)
// ---------------------------------------------------------------------------
__global__ void scatter_kernel(const int* __restrict__ src, const int* __restrict__ dst,
                               const float* __restrict__ ew, const float* __restrict__ dinv,
                               const float* __restrict__ h, float* __restrict__ acc) {
    int e = blockIdx.x * 4 + (threadIdx.x >> 6);
    if (e >= N_EDGES) return;
    int lane = threadIdx.x & 63;
    int s = src[e];
    int d = dst[e];
    float w = ew[e] * dinv[s] * dinv[d];
    float2 v = ((const float2*)(h + (size_t)s * D))[lane];
    float* ap = acc + (size_t)d * D + lane * 2;
    atomicAdd(ap,     v.x * w);
    atomicAdd(ap + 1, v.y * w);
}

__global__ void finalize_kernel(const float* __restrict__ h, const float* __restrict__ dinv,
                                const float* __restrict__ b, float* __restrict__ out) {
    int i = blockIdx.x * 256 + threadIdx.x;
    if (i >= N_NODES * D) return;
    int node = i >> 7;
    int col  = i & 127;
    float di = dinv[node];
    float v = out[i] + h[i] * di * di + b[col];
    out[i] = fmaxf(v, 0.0f);
}

extern "C" void kernel_launch(void* const* d_in, const int* in_sizes, int n_in,
                              void* d_out, int out_size, void* d_ws, size_t ws_size,
                              hipStream_t stream) {
    const float* x  = (const float*)d_in[0];
    const int*   ei = (const int*)d_in[1];   // [2, E]: src row then dst row
    const float* ew = (const float*)d_in[2];
    const float* W  = (const float*)d_in[3];
    const float* b  = (const float*)d_in[4];
    float*       out = (float*)d_out;

    const int* src = ei;
    const int* dst = ei + N_EDGES;

    // workspace layout (all 4 B elements)
    float*  h         = (float*)d_ws;                         // N*D
    float*  deg       = h + (size_t)N_NODES * D;              // N
    float*  dinv      = deg + N_NODES;                        // N
    int*    cnt       = (int*)(dinv + N_NODES);               // N
    int*    off       = cnt + N_NODES;                        // N+1
    int*    blockSums = off + (N_NODES + 1);                  // SCAN_B
    int*    srcs_s    = blockSums + SCAN_B;                   // E
    float*  w_s       = (float*)(srcs_s + N_EDGES);           // E
    ushort* wfh       = (ushort*)(w_s + N_EDGES);             // 8*4*64*8 = 16384
    ushort* wfl       = wfh + 16384;                          // 16384
    size_t need = ((size_t)(wfl + 16384) - (size_t)d_ws);

    if (ws_size >= need) {
        // ---------------- CSR gather + MFMA GEMM path ----------------
        init_kernel<<<(N_NODES + 255) / 256, 256, 0, stream>>>(deg, cnt);
        deg_cnt_kernel<<<(N_EDGES + 255) / 256, 256, 0, stream>>>(dst, ew, deg, cnt);
        dinv_kernel<<<(N_NODES + 255) / 256, 256, 0, stream>>>(deg, dinv);

        scan1_kernel<<<NB, SCAN_B, 0, stream>>>(cnt, blockSums);
        scan2_kernel<<<1, SCAN_B, 0, stream>>>(blockSums);
        scan3_kernel<<<NB, SCAN_B, 0, stream>>>(cnt, blockSums, off);

        fill_kernel<<<(N_EDGES + 255) / 256, 256, 0, stream>>>(src, dst, ew, dinv,
                                                               cnt, srcs_s, w_s);

        wfrag_kernel<<<8, 256, 0, stream>>>(W, wfh, wfl);
        gemm_mfma_kernel<<<(N_NODES + 63) / 64, 256, 0, stream>>>(x, wfh, wfl, h);

        gather_kernel<<<(N_NODES + 3) / 4, 256, 0, stream>>>(off, srcs_s, w_s, dinv,
                                                             h, b, out);
    } else {
        // ---------------- fallback: atomic scatter ----------------
        hipMemsetAsync(d_out, 0, (size_t)out_size * sizeof(float), stream);
        init_kernel<<<(N_NODES + 255) / 256, 256, 0, stream>>>(deg, cnt);
        deg_cnt_kernel<<<(N_EDGES + 255) / 256, 256, 0, stream>>>(dst, ew, deg, cnt);
        dinv_kernel<<<(N_NODES + 255) / 256, 256, 0, stream>>>(deg, dinv);
        gemm_xw_kernel<<<(N_NODES + 1) / 2, 256, 0, stream>>>(x, W, h);
        scatter_kernel<<<(N_EDGES + 3) / 4, 256, 0, stream>>>(src, dst, ew, dinv, h, out);
        finalize_kernel<<<(N_NODES * D + 255) / 256, 256, 0, stream>>>(h, dinv, b, out);
    }
}

// Round 4
// 138.448 us; speedup vs baseline: 4.7268x; 1.3154x over previous
//
#include <hip/hip_runtime.h>

#define N_NODES 50000
#define N_EDGES 600000
#define D 128
#define SCAN_B 256
#define NB ((N_NODES + SCAN_B - 1) / SCAN_B)   // 196 blocks
#define REP 8
#define FXSHIFT 44                              // count in bits [44,64), fx24 sum in [0,44)

typedef __attribute__((ext_vector_type(8))) short short8;
typedef __attribute__((ext_vector_type(4))) float f32x4;
typedef unsigned long long u64;

__device__ __forceinline__ ushort f2bf(float f) {
    unsigned u = __float_as_uint(f);
    unsigned r = (u + 0x7FFFu + ((u >> 16) & 1u)) >> 16;   // RNE
    return (ushort)r;
}
__device__ __forceinline__ float bf2f(ushort h) {
    return __uint_as_float(((unsigned)h) << 16);
}

// ---------------------------------------------------------------------------
// Per-edge: one packed u64 atomic into one of 8 replicas.
// packed = (1 << FXSHIFT) | round(ew * 2^24)
// ---------------------------------------------------------------------------
__global__ void deg_cnt_kernel(const int* __restrict__ dst,
                               const float* __restrict__ ew,
                               u64* __restrict__ degp) {
    int e = blockIdx.x * 256 + threadIdx.x;
    if (e < N_EDGES) {
        int d = dst[e];
        int r = blockIdx.x & (REP - 1);
        u64 fx = (u64)llrintf(ew[e] * 16777216.0f);
        atomicAdd(&degp[(size_t)r * N_NODES + d], (1ull << FXSHIFT) | fx);
    }
}

// ---------------------------------------------------------------------------
// scan1 (fused with dinv): sum 8 replicas -> deg/dinv + count; block-local
// exclusive scan of counts into cnt; block sums out.
// ---------------------------------------------------------------------------
__global__ void scan1_kernel(const u64* __restrict__ degp,
                             float* __restrict__ dinv,
                             int* __restrict__ cnt,
                             int* __restrict__ blockSums) {
    __shared__ int s[SCAN_B];
    int t = threadIdx.x;
    int i = blockIdx.x * SCAN_B + t;
    int v = 0;
    if (i < N_NODES) {
        u64 fxsum = 0;
        int c = 0;
#pragma unroll
        for (int r = 0; r < REP; ++r) {
            u64 p = degp[(size_t)r * N_NODES + i];
            fxsum += p & ((1ull << FXSHIFT) - 1);
            c += (int)(p >> FXSHIFT);
        }
        float deg = 1.0f + (float)fxsum * (1.0f / 16777216.0f);
        dinv[i] = rsqrtf(deg);          // deg >= 1 always
        v = c;
    }
    s[t] = v;
    __syncthreads();
    for (int o = 1; o < SCAN_B; o <<= 1) {
        int x = (t >= o) ? s[t - o] : 0;
        __syncthreads();
        s[t] += x;
        __syncthreads();
    }
    if (i < N_NODES) cnt[i] = s[t] - v;
    if (t == SCAN_B - 1) blockSums[blockIdx.x] = s[t];
}

__global__ void scan2_kernel(int* __restrict__ blockSums) {
    __shared__ int s[SCAN_B];
    int t = threadIdx.x;
    int v = (t < NB) ? blockSums[t] : 0;
    s[t] = v;
    __syncthreads();
    for (int o = 1; o < SCAN_B; o <<= 1) {
        int x = (t >= o) ? s[t - o] : 0;
        __syncthreads();
        s[t] += x;
        __syncthreads();
    }
    if (t < NB) blockSums[t] = s[t] - v;
}

// off[i] + per-replica fill cursors (8-way partitioned by edge block)
__global__ void scan3_kernel(const u64* __restrict__ degp,
                             const int* __restrict__ cnt,
                             const int* __restrict__ blockSums,
                             int* __restrict__ off,
                             int* __restrict__ cursor) {
    int i = blockIdx.x * SCAN_B + threadIdx.x;
    if (i < N_NODES) {
        int o = cnt[i] + blockSums[blockIdx.x];
        off[i] = o;
        int run = o;
#pragma unroll
        for (int r = 0; r < REP; ++r) {
            cursor[(size_t)r * N_NODES + i] = run;
            run += (int)(degp[(size_t)r * N_NODES + i] >> FXSHIFT);
        }
    }
    if (i == 0) off[N_NODES] = N_EDGES;
}

// ---------------------------------------------------------------------------
// Fill dst-sorted packed edge array: (norm_bits << 32) | src
// ---------------------------------------------------------------------------
__global__ void fill_kernel(const int* __restrict__ src, const int* __restrict__ dst,
                            const float* __restrict__ ew, const float* __restrict__ dinv,
                            int* __restrict__ cursor,
                            u64* __restrict__ edge_s) {
    int e = blockIdx.x * 256 + threadIdx.x;
    if (e >= N_EDGES) return;
    int s = src[e];
    int d = dst[e];
    int r = blockIdx.x & (REP - 1);
    int pos = atomicAdd(&cursor[(size_t)r * N_NODES + d], 1);
    float w = ew[e] * dinv[s] * dinv[d];
    edge_s[pos] = ((u64)__float_as_uint(w) << 32) | (unsigned)s;
}

// ---------------------------------------------------------------------------
// W fragment precompute (hi/lo bf16 split), MFMA B-operand lane order.
// ---------------------------------------------------------------------------
__global__ void wfrag_kernel(const float* __restrict__ W,
                             ushort* __restrict__ wfh, ushort* __restrict__ wfl) {
    int t = blockIdx.x * 256 + threadIdx.x;    // 2048 threads total
    int lane = t & 63;
    int ks   = (t >> 6) & 3;
    int ct   = t >> 8;
    int n  = ct * 16 + (lane & 15);
    int k0 = ks * 32 + (lane >> 4) * 8;
    ushort hv[8], lv[8];
#pragma unroll
    for (int j = 0; j < 8; ++j) {
        float v = W[(k0 + j) * D + n];
        ushort hh = f2bf(v);
        hv[j] = hh;
        lv[j] = f2bf(v - bf2f(hh));
    }
    size_t base = (((size_t)ct * 4 + ks) * 64 + lane) * 8;
#pragma unroll
    for (int j = 0; j < 8; ++j) { wfh[base + j] = hv[j]; wfl[base + j] = lv[j]; }
}

// ---------------------------------------------------------------------------
// h = x @ W via bf16 MFMA hi/lo split; writes h as bf16.
// ---------------------------------------------------------------------------
__global__ __launch_bounds__(256) void gemm_mfma_kernel(
        const float* __restrict__ x,
        const ushort* __restrict__ wfh, const ushort* __restrict__ wfl,
        ushort* __restrict__ hbf) {
    __shared__ __attribute__((aligned(16))) ushort xh[64 * 128];
    __shared__ __attribute__((aligned(16))) ushort xl[64 * 128];

    int t  = threadIdx.x;
    int r0 = blockIdx.x * 64;

#pragma unroll
    for (int p = 0; p < 8; ++p) {
        int row  = p * 8 + (t >> 5);
        int g    = t & 31;
        int grow = r0 + row;
        float4 v = make_float4(0.f, 0.f, 0.f, 0.f);
        if (grow < N_NODES) v = ((const float4*)(x + (size_t)grow * D))[g];
        ushort4 hi, lo;
        hi.x = f2bf(v.x); lo.x = f2bf(v.x - bf2f(hi.x));
        hi.y = f2bf(v.y); lo.y = f2bf(v.y - bf2f(hi.y));
        hi.z = f2bf(v.z); lo.z = f2bf(v.z - bf2f(hi.z));
        hi.w = f2bf(v.w); lo.w = f2bf(v.w - bf2f(hi.w));
        int bo = (row * 256 + g * 8) ^ ((row & 7) << 4);
        *(ushort4*)((char*)xh + bo) = hi;
        *(ushort4*)((char*)xl + bo) = lo;
    }
    __syncthreads();

    int w  = t >> 6;
    int l  = t & 63;
    int m  = l & 15;
    int gq = l >> 4;

    f32x4 acc[8];
#pragma unroll
    for (int ct = 0; ct < 8; ++ct) acc[ct] = (f32x4){0.f, 0.f, 0.f, 0.f};

#pragma unroll
    for (int ks = 0; ks < 4; ++ks) {
        int row = w * 16 + m;
        int bo  = (row * 256 + gq * 16 + ks * 64) ^ ((row & 7) << 4);
        short8 ah = *(const short8*)((const char*)xh + bo);
        short8 al = *(const short8*)((const char*)xl + bo);
#pragma unroll
        for (int ct = 0; ct < 8; ++ct) {
            size_t fb = (((size_t)ct * 4 + ks) * 64 + l) * 8;
            short8 bh = *(const short8*)(wfh + fb);
            short8 bl = *(const short8*)(wfl + fb);
            acc[ct] = __builtin_amdgcn_mfma_f32_16x16x32_bf16(ah, bh, acc[ct], 0, 0, 0);
            acc[ct] = __builtin_amdgcn_mfma_f32_16x16x32_bf16(al, bh, acc[ct], 0, 0, 0);
            acc[ct] = __builtin_amdgcn_mfma_f32_16x16x32_bf16(ah, bl, acc[ct], 0, 0, 0);
        }
    }

    int orow0 = r0 + w * 16 + gq * 4;
#pragma unroll
    for (int ct = 0; ct < 8; ++ct) {
#pragma unroll
        for (int r = 0; r < 4; ++r) {
            int row = orow0 + r;
            if (row < N_NODES) hbf[(size_t)row * D + ct * 16 + m] = f2bf(acc[ct][r]);
        }
    }
}

// ---------------------------------------------------------------------------
// Gather: one wave per node; bf16 h rows; packed (norm,src) edge meta.
// ---------------------------------------------------------------------------
__global__ __launch_bounds__(256) void gather_kernel(
        const int* __restrict__ off, const u64* __restrict__ edge_s,
        const float* __restrict__ dinv,
        const ushort* __restrict__ hbf, const float* __restrict__ b,
        float* __restrict__ out) {
    int node = blockIdx.x * 4 + (threadIdx.x >> 6);
    if (node >= N_NODES) return;
    int lane = threadIdx.x & 63;

    int begin = off[node];
    int end   = off[node + 1];
    float dd  = dinv[node];

    ushort2 sv = ((const ushort2*)(hbf + (size_t)node * D))[lane];
    float sw = dd * dd;
    float accx = bf2f(sv.x) * sw;
    float accy = bf2f(sv.y) * sw;

    for (int j0 = begin; j0 < end; j0 += 64) {
        int n = end - j0;
        if (n > 64) n = 64;
        u64 p = 0;
        if (lane < n) p = edge_s[j0 + lane];
        for (int t = 0; t < n; ++t) {
            u64 pe = __shfl((long long)p, t);
            int   ss = (int)(pe & 0xFFFFFFFFu);
            float ww = __uint_as_float((unsigned)(pe >> 32));
            ushort2 v = ((const ushort2*)(hbf + (size_t)ss * D))[lane];
            accx = fmaf(bf2f(v.x), ww, accx);
            accy = fmaf(bf2f(v.y), ww, accy);
        }
    }
    float2 bb = ((const float2*)b)[lane];
    float2 o2 = make_float2(fmaxf(accx + bb.x, 0.0f), fmaxf(accy + bb.y, 0.0f));
    *(float2*)(out + (size_t)node * D + lane * 2) = o2;
}

// ---------------------------------------------------------------------------
// Fallback path (small ws): R0-style atomic scatter, f32 throughout.
// ---------------------------------------------------------------------------
__global__ void fb_init_kernel(float* __restrict__ deg) {
    int i = blockIdx.x * 256 + threadIdx.x;
    if (i < N_NODES) deg[i] = 1.0f;
}
__global__ void fb_deg_kernel(const int* __restrict__ dst, const float* __restrict__ ew,
                              float* __restrict__ deg) {
    int e = blockIdx.x * 256 + threadIdx.x;
    if (e < N_EDGES) atomicAdd(&deg[dst[e]], ew[e]);
}
__global__ void fb_dinv_kernel(const float* __restrict__ deg, float* __restrict__ dinv) {
    int i = blockIdx.x * 256 + threadIdx.x;
    if (i < N_NODES) {
        float d = deg[i];
        dinv[i] = (d > 0.0f) ? rsqrtf(d) : 0.0f;
    }
}
__global__ void fb_gemm_kernel(const float* __restrict__ x, const float* __restrict__ W,
                               float* __restrict__ h) {
    __shared__ float xs[2][D];
    int lr  = threadIdx.x >> 7;
    int col = threadIdx.x & 127;
    int row = blockIdx.x * 2 + lr;
    if (row < N_NODES) xs[lr][col] = x[(size_t)row * D + col];
    __syncthreads();
    if (row >= N_NODES) return;
    float acc = 0.0f;
#pragma unroll 8
    for (int k = 0; k < D; ++k) acc = fmaf(xs[lr][k], W[k * D + col], acc);
    h[(size_t)row * D + col] = acc;
}
__global__ void fb_scatter_kernel(const int* __restrict__ src, const int* __restrict__ dst,
                                  const float* __restrict__ ew, const float* __restrict__ dinv,
                                  const float* __restrict__ h, float* __restrict__ acc) {
    int e = blockIdx.x * 4 + (threadIdx.x >> 6);
    if (e >= N_EDGES) return;
    int lane = threadIdx.x & 63;
    int s = src[e];
    int d = dst[e];
    float w = ew[e] * dinv[s] * dinv[d];
    float2 v = ((const float2*)(h + (size_t)s * D))[lane];
    float* ap = acc + (size_t)d * D + lane * 2;
    atomicAdd(ap,     v.x * w);
    atomicAdd(ap + 1, v.y * w);
}
__global__ void fb_finalize_kernel(const float* __restrict__ h, const float* __restrict__ dinv,
                                   const float* __restrict__ b, float* __restrict__ out) {
    int i = blockIdx.x * 256 + threadIdx.x;
    if (i >= N_NODES * D) return;
    int node = i >> 7;
    int col  = i & 127;
    float di = dinv[node];
    float v = out[i] + h[i] * di * di + b[col];
    out[i] = fmaxf(v, 0.0f);
}

extern "C" void kernel_launch(void* const* d_in, const int* in_sizes, int n_in,
                              void* d_out, int out_size, void* d_ws, size_t ws_size,
                              hipStream_t stream) {
    const float* x  = (const float*)d_in[0];
    const int*   ei = (const int*)d_in[1];   // [2, E]: src row then dst row
    const float* ew = (const float*)d_in[2];
    const float* W  = (const float*)d_in[3];
    const float* b  = (const float*)d_in[4];
    float*       out = (float*)d_out;

    const int* src = ei;
    const int* dst = ei + N_EDGES;

    // ---- main-path workspace layout ----
    ushort* hbf      = (ushort*)d_ws;                          // N*D bf16   (12.8 MB)
    u64*    degp     = (u64*)(hbf + (size_t)N_NODES * D);      // REP*N u64  (3.2 MB)
    float*  dinv     = (float*)(degp + (size_t)REP * N_NODES); // N
    int*    cnt      = (int*)(dinv + N_NODES);                 // N
    int*    off      = cnt + N_NODES;                          // N+1
    int*    blockSums= off + (N_NODES + 1);                    // SCAN_B
    int*    cursor   = blockSums + SCAN_B;                     // REP*N      (1.6 MB)
    u64*    edge_s   = (u64*)(cursor + (size_t)REP * N_NODES); // E u64      (4.8 MB)
    ushort* wfh      = (ushort*)(edge_s + N_EDGES);            // 16384
    ushort* wfl      = wfh + 16384;                            // 16384
    size_t need = ((size_t)(wfl + 16384) - (size_t)d_ws);

    if (ws_size >= need) {
        hipMemsetAsync(degp, 0, (size_t)REP * N_NODES * sizeof(u64), stream);

        deg_cnt_kernel<<<(N_EDGES + 255) / 256, 256, 0, stream>>>(dst, ew, degp);
        scan1_kernel<<<NB, SCAN_B, 0, stream>>>(degp, dinv, cnt, blockSums);
        scan2_kernel<<<1, SCAN_B, 0, stream>>>(blockSums);
        scan3_kernel<<<NB, SCAN_B, 0, stream>>>(degp, cnt, blockSums, off, cursor);

        fill_kernel<<<(N_EDGES + 255) / 256, 256, 0, stream>>>(src, dst, ew, dinv,
                                                               cursor, edge_s);

        wfrag_kernel<<<8, 256, 0, stream>>>(W, wfh, wfl);
        gemm_mfma_kernel<<<(N_NODES + 63) / 64, 256, 0, stream>>>(x, wfh, wfl, hbf);

        gather_kernel<<<(N_NODES + 3) / 4, 256, 0, stream>>>(off, edge_s, dinv,
                                                             hbf, b, out);
    } else {
        // ---- fallback: atomic scatter, f32 ----
        float* h    = (float*)d_ws;                 // N*D
        float* deg  = h + (size_t)N_NODES * D;      // N
        float* dv   = deg + N_NODES;                // N
        hipMemsetAsync(d_out, 0, (size_t)out_size * sizeof(float), stream);
        fb_init_kernel<<<(N_NODES + 255) / 256, 256, 0, stream>>>(deg);
        fb_deg_kernel<<<(N_EDGES + 255) / 256, 256, 0, stream>>>(dst, ew, deg);
        fb_dinv_kernel<<<(N_NODES + 255) / 256, 256, 0, stream>>>(deg, dv);
        fb_gemm_kernel<<<(N_NODES + 1) / 2, 256, 0, stream>>>(x, W, h);
        fb_scatter_kernel<<<(N_EDGES + 3) / 4, 256, 0, stream>>>(src, dst, ew, dv, h, out);
        fb_finalize_kernel<<<(N_NODES * D + 255) / 256, 256, 0, stream>>>(h, dv, b, out);
    }
}

// Round 5
// 129.182 us; speedup vs baseline: 5.0659x; 1.0717x over previous
//
#include <hip/hip_runtime.h>

#define N_NODES 50000
#define N_EDGES 600000
#define D 128
#define SCAN_B 256
#define NB ((N_NODES + SCAN_B - 1) / SCAN_B)   // 196 blocks
#define REP 8
#define FXSHIFT 44                              // count in bits [44,64), fx24 sum in [0,44)

typedef __attribute__((ext_vector_type(8))) short short8;
typedef __attribute__((ext_vector_type(4))) float f32x4;
typedef unsigned long long u64;

__device__ __forceinline__ ushort f2bf(float f) {
    unsigned u = __float_as_uint(f);
    unsigned r = (u + 0x7FFFu + ((u >> 16) & 1u)) >> 16;   // RNE
    return (ushort)r;
}
__device__ __forceinline__ float bf2f(ushort h) {
    return __uint_as_float(((unsigned)h) << 16);
}

// ---------------------------------------------------------------------------
// Per-edge: one packed u64 atomic into one of 8 replicas.
// ---------------------------------------------------------------------------
__global__ void deg_cnt_kernel(const int* __restrict__ dst,
                               const float* __restrict__ ew,
                               u64* __restrict__ degp) {
    int e = blockIdx.x * 256 + threadIdx.x;
    if (e < N_EDGES) {
        int d = dst[e];
        int r = blockIdx.x & (REP - 1);
        u64 fx = (u64)llrintf(ew[e] * 16777216.0f);
        atomicAdd(&degp[(size_t)r * N_NODES + d], (1ull << FXSHIFT) | fx);
    }
}

// ---------------------------------------------------------------------------
// scan1 (fused with dinv): replica-sum -> dinv + count; block-local exclusive
// scan; raw block sums out.
// ---------------------------------------------------------------------------
__global__ void scan1_kernel(const u64* __restrict__ degp,
                             float* __restrict__ dinv,
                             int* __restrict__ cnt,
                             int* __restrict__ blockSums) {
    __shared__ int s[SCAN_B];
    int t = threadIdx.x;
    int i = blockIdx.x * SCAN_B + t;
    int v = 0;
    if (i < N_NODES) {
        u64 fxsum = 0;
        int c = 0;
#pragma unroll
        for (int r = 0; r < REP; ++r) {
            u64 p = degp[(size_t)r * N_NODES + i];
            fxsum += p & ((1ull << FXSHIFT) - 1);
            c += (int)(p >> FXSHIFT);
        }
        float deg = 1.0f + (float)fxsum * (1.0f / 16777216.0f);
        dinv[i] = rsqrtf(deg);          // deg >= 1 always
        v = c;
    }
    s[t] = v;
    __syncthreads();
    for (int o = 1; o < SCAN_B; o <<= 1) {
        int x = (t >= o) ? s[t - o] : 0;
        __syncthreads();
        s[t] += x;
        __syncthreads();
    }
    if (i < N_NODES) cnt[i] = s[t] - v;
    if (t == SCAN_B - 1) blockSums[blockIdx.x] = s[t];
}

// off[i] + per-replica fill cursors; scan of raw blockSums folded in (thread 0
// serially sums <=196 values -- cheaper than a separate dispatch).
__global__ void scan3_kernel(const u64* __restrict__ degp,
                             const int* __restrict__ cnt,
                             const int* __restrict__ blockSums,
                             int* __restrict__ off,
                             int* __restrict__ cursor) {
    __shared__ int sbase;
    if (threadIdx.x == 0) {
        int s = 0;
        for (int r = 0; r < blockIdx.x; ++r) s += blockSums[r];
        sbase = s;
    }
    __syncthreads();
    int i = blockIdx.x * SCAN_B + threadIdx.x;
    if (i < N_NODES) {
        int o = cnt[i] + sbase;
        off[i] = o;
        int run = o;
#pragma unroll
        for (int r = 0; r < REP; ++r) {
            cursor[(size_t)r * N_NODES + i] = run;
            run += (int)(degp[(size_t)r * N_NODES + i] >> FXSHIFT);
        }
    }
    if (i == 0) off[N_NODES] = N_EDGES;
}

// ---------------------------------------------------------------------------
// Fill dst-sorted packed edge array: (norm_bits << 32) | src
// ---------------------------------------------------------------------------
__global__ void fill_kernel(const int* __restrict__ src, const int* __restrict__ dst,
                            const float* __restrict__ ew, const float* __restrict__ dinv,
                            int* __restrict__ cursor,
                            u64* __restrict__ edge_s) {
    int e = blockIdx.x * 256 + threadIdx.x;
    if (e >= N_EDGES) return;
    int s = src[e];
    int d = dst[e];
    int r = blockIdx.x & (REP - 1);
    int pos = atomicAdd(&cursor[(size_t)r * N_NODES + d], 1);
    float w = ew[e] * dinv[s] * dinv[d];
    edge_s[pos] = ((u64)__float_as_uint(w) << 32) | (unsigned)s;
}

// ---------------------------------------------------------------------------
// W fragment precompute (hi/lo bf16 split), MFMA B-operand lane order.
// ---------------------------------------------------------------------------
__global__ void wfrag_kernel(const float* __restrict__ W,
                             ushort* __restrict__ wfh, ushort* __restrict__ wfl) {
    int t = blockIdx.x * 256 + threadIdx.x;    // 2048 threads total
    int lane = t & 63;
    int ks   = (t >> 6) & 3;
    int ct   = t >> 8;
    int n  = ct * 16 + (lane & 15);
    int k0 = ks * 32 + (lane >> 4) * 8;
    ushort hv[8], lv[8];
#pragma unroll
    for (int j = 0; j < 8; ++j) {
        float v = W[(k0 + j) * D + n];
        ushort hh = f2bf(v);
        hv[j] = hh;
        lv[j] = f2bf(v - bf2f(hh));
    }
    size_t base = (((size_t)ct * 4 + ks) * 64 + lane) * 8;
#pragma unroll
    for (int j = 0; j < 8; ++j) { wfh[base + j] = hv[j]; wfl[base + j] = lv[j]; }
}

// ---------------------------------------------------------------------------
// h = x @ W via bf16 MFMA hi/lo split; writes h as bf16.
// ---------------------------------------------------------------------------
__global__ __launch_bounds__(256) void gemm_mfma_kernel(
        const float* __restrict__ x,
        const ushort* __restrict__ wfh, const ushort* __restrict__ wfl,
        ushort* __restrict__ hbf) {
    __shared__ __attribute__((aligned(16))) ushort xh[64 * 128];
    __shared__ __attribute__((aligned(16))) ushort xl[64 * 128];

    int t  = threadIdx.x;
    int r0 = blockIdx.x * 64;

#pragma unroll
    for (int p = 0; p < 8; ++p) {
        int row  = p * 8 + (t >> 5);
        int g    = t & 31;
        int grow = r0 + row;
        float4 v = make_float4(0.f, 0.f, 0.f, 0.f);
        if (grow < N_NODES) v = ((const float4*)(x + (size_t)grow * D))[g];
        ushort4 hi, lo;
        hi.x = f2bf(v.x); lo.x = f2bf(v.x - bf2f(hi.x));
        hi.y = f2bf(v.y); lo.y = f2bf(v.y - bf2f(hi.y));
        hi.z = f2bf(v.z); lo.z = f2bf(v.z - bf2f(hi.z));
        hi.w = f2bf(v.w); lo.w = f2bf(v.w - bf2f(hi.w));
        int bo = (row * 256 + g * 8) ^ ((row & 7) << 4);
        *(ushort4*)((char*)xh + bo) = hi;
        *(ushort4*)((char*)xl + bo) = lo;
    }
    __syncthreads();

    int w  = t >> 6;
    int l  = t & 63;
    int m  = l & 15;
    int gq = l >> 4;

    f32x4 acc[8];
#pragma unroll
    for (int ct = 0; ct < 8; ++ct) acc[ct] = (f32x4){0.f, 0.f, 0.f, 0.f};

#pragma unroll
    for (int ks = 0; ks < 4; ++ks) {
        int row = w * 16 + m;
        int bo  = (row * 256 + gq * 16 + ks * 64) ^ ((row & 7) << 4);
        short8 ah = *(const short8*)((const char*)xh + bo);
        short8 al = *(const short8*)((const char*)xl + bo);
#pragma unroll
        for (int ct = 0; ct < 8; ++ct) {
            size_t fb = (((size_t)ct * 4 + ks) * 64 + l) * 8;
            short8 bh = *(const short8*)(wfh + fb);
            short8 bl = *(const short8*)(wfl + fb);
            acc[ct] = __builtin_amdgcn_mfma_f32_16x16x32_bf16(ah, bh, acc[ct], 0, 0, 0);
            acc[ct] = __builtin_amdgcn_mfma_f32_16x16x32_bf16(al, bh, acc[ct], 0, 0, 0);
            acc[ct] = __builtin_amdgcn_mfma_f32_16x16x32_bf16(ah, bl, acc[ct], 0, 0, 0);
        }
    }

    int orow0 = r0 + w * 16 + gq * 4;
#pragma unroll
    for (int ct = 0; ct < 8; ++ct) {
#pragma unroll
        for (int r = 0; r < 4; ++r) {
            int row = orow0 + r;
            if (row < N_NODES) hbf[(size_t)row * D + ct * 16 + m] = f2bf(acc[ct][r]);
        }
    }
}

// ---------------------------------------------------------------------------
// Gather: one wave per node, SPLIT-WAVE: 32 lanes cover the 128-feature row
// (ushort4 = 8B/lane), the two wave halves process disjoint halves of the
// node's edge list concurrently. Cross-half combine via shfl_xor(32).
// ---------------------------------------------------------------------------
__global__ __launch_bounds__(256) void gather_kernel(
        const int* __restrict__ off, const u64* __restrict__ edge_s,
        const float* __restrict__ dinv,
        const ushort* __restrict__ hbf, const float* __restrict__ b,
        float* __restrict__ out) {
    int node = blockIdx.x * 4 + (threadIdx.x >> 6);
    if (node >= N_NODES) return;
    int lane = threadIdx.x & 63;
    int half = lane >> 5;       // 0 or 1
    int fl   = lane & 31;       // feature group: 4*fl .. 4*fl+3

    int begin = off[node];
    int end   = off[node + 1];
    float dd  = dinv[node];
    float sw  = dd * dd;

    // self-loop contribution on half 0 only
    ushort4 sv = ((const ushort4*)(hbf + (size_t)node * D))[fl];
    float4 acc = make_float4(0.f, 0.f, 0.f, 0.f);
    if (half == 0) {
        acc.x = bf2f(sv.x) * sw; acc.y = bf2f(sv.y) * sw;
        acc.z = bf2f(sv.z) * sw; acc.w = bf2f(sv.w) * sw;
    }

    for (int j0 = begin; j0 < end; j0 += 64) {
        int nc = end - j0;
        if (nc > 64) nc = 64;
        u64 p = 0;
        if (lane < nc) p = edge_s[j0 + lane];
        int nA   = (nc + 1) >> 1;            // half A: edges [0,nA), half B: [nA,nc)
        int base = half ? nA : 0;
        int lim  = half ? (nc - nA) : nA;
#pragma unroll 2
        for (int t = 0; t < nA; ++t) {
            u64 pe = __shfl((long long)p, base + t);
            bool valid = t < lim;
            int   ss = valid ? (int)(pe & 0xFFFFFFFFu) : 0;
            float ww = valid ? __uint_as_float((unsigned)(pe >> 32)) : 0.0f;
            ushort4 v = ((const ushort4*)(hbf + (size_t)ss * D))[fl];
            acc.x = fmaf(bf2f(v.x), ww, acc.x);
            acc.y = fmaf(bf2f(v.y), ww, acc.y);
            acc.z = fmaf(bf2f(v.z), ww, acc.z);
            acc.w = fmaf(bf2f(v.w), ww, acc.w);
        }
    }

    // combine halves
    acc.x += __shfl_xor(acc.x, 32);
    acc.y += __shfl_xor(acc.y, 32);
    acc.z += __shfl_xor(acc.z, 32);
    acc.w += __shfl_xor(acc.w, 32);

    if (half == 0) {
        float4 bb = ((const float4*)b)[fl];
        float4 o4 = make_float4(fmaxf(acc.x + bb.x, 0.f), fmaxf(acc.y + bb.y, 0.f),
                                fmaxf(acc.z + bb.z, 0.f), fmaxf(acc.w + bb.w, 0.f));
        ((float4*)(out + (size_t)node * D))[fl] = o4;
    }
}

// ---------------------------------------------------------------------------
// Fallback path (small ws): R0-style atomic scatter, f32 throughout.
// ---------------------------------------------------------------------------
__global__ void fb_init_kernel(float* __restrict__ deg) {
    int i = blockIdx.x * 256 + threadIdx.x;
    if (i < N_NODES) deg[i] = 1.0f;
}
__global__ void fb_deg_kernel(const int* __restrict__ dst, const float* __restrict__ ew,
                              float* __restrict__ deg) {
    int e = blockIdx.x * 256 + threadIdx.x;
    if (e < N_EDGES) atomicAdd(&deg[dst[e]], ew[e]);
}
__global__ void fb_dinv_kernel(const float* __restrict__ deg, float* __restrict__ dinv) {
    int i = blockIdx.x * 256 + threadIdx.x;
    if (i < N_NODES) {
        float d = deg[i];
        dinv[i] = (d > 0.0f) ? rsqrtf(d) : 0.0f;
    }
}
__global__ void fb_gemm_kernel(const float* __restrict__ x, const float* __restrict__ W,
                               float* __restrict__ h) {
    __shared__ float xs[2][D];
    int lr  = threadIdx.x >> 7;
    int col = threadIdx.x & 127;
    int row = blockIdx.x * 2 + lr;
    if (row < N_NODES) xs[lr][col] = x[(size_t)row * D + col];
    __syncthreads();
    if (row >= N_NODES) return;
    float acc = 0.0f;
#pragma unroll 8
    for (int k = 0; k < D; ++k) acc = fmaf(xs[lr][k], W[k * D + col], acc);
    h[(size_t)row * D + col] = acc;
}
__global__ void fb_scatter_kernel(const int* __restrict__ src, const int* __restrict__ dst,
                                  const float* __restrict__ ew, const float* __restrict__ dinv,
                                  const float* __restrict__ h, float* __restrict__ acc) {
    int e = blockIdx.x * 4 + (threadIdx.x >> 6);
    if (e >= N_EDGES) return;
    int lane = threadIdx.x & 63;
    int s = src[e];
    int d = dst[e];
    float w = ew[e] * dinv[s] * dinv[d];
    float2 v = ((const float2*)(h + (size_t)s * D))[lane];
    float* ap = acc + (size_t)d * D + lane * 2;
    atomicAdd(ap,     v.x * w);
    atomicAdd(ap + 1, v.y * w);
}
__global__ void fb_finalize_kernel(const float* __restrict__ h, const float* __restrict__ dinv,
                                   const float* __restrict__ b, float* __restrict__ out) {
    int i = blockIdx.x * 256 + threadIdx.x;
    if (i >= N_NODES * D) return;
    int node = i >> 7;
    int col  = i & 127;
    float di = dinv[node];
    float v = out[i] + h[i] * di * di + b[col];
    out[i] = fmaxf(v, 0.0f);
}

extern "C" void kernel_launch(void* const* d_in, const int* in_sizes, int n_in,
                              void* d_out, int out_size, void* d_ws, size_t ws_size,
                              hipStream_t stream) {
    const float* x  = (const float*)d_in[0];
    const int*   ei = (const int*)d_in[1];   // [2, E]: src row then dst row
    const float* ew = (const float*)d_in[2];
    const float* W  = (const float*)d_in[3];
    const float* b  = (const float*)d_in[4];
    float*       out = (float*)d_out;

    const int* src = ei;
    const int* dst = ei + N_EDGES;

    // ---- main-path workspace layout ----
    ushort* hbf      = (ushort*)d_ws;                          // N*D bf16   (12.8 MB)
    u64*    degp     = (u64*)(hbf + (size_t)N_NODES * D);      // REP*N u64  (3.2 MB)
    float*  dinv     = (float*)(degp + (size_t)REP * N_NODES); // N
    int*    cnt      = (int*)(dinv + N_NODES);                 // N
    int*    off      = cnt + N_NODES;                          // N+1
    int*    blockSums= off + (N_NODES + 1);                    // SCAN_B
    int*    cursor   = blockSums + SCAN_B;                     // REP*N      (1.6 MB)
    u64*    edge_s   = (u64*)(cursor + (size_t)REP * N_NODES); // E u64      (4.8 MB)
    ushort* wfh      = (ushort*)(edge_s + N_EDGES);            // 16384
    ushort* wfl      = wfh + 16384;                            // 16384
    size_t need = ((size_t)(wfl + 16384) - (size_t)d_ws);

    if (ws_size >= need) {
        hipMemsetAsync(degp, 0, (size_t)REP * N_NODES * sizeof(u64), stream);

        deg_cnt_kernel<<<(N_EDGES + 255) / 256, 256, 0, stream>>>(dst, ew, degp);
        scan1_kernel<<<NB, SCAN_B, 0, stream>>>(degp, dinv, cnt, blockSums);
        scan3_kernel<<<NB, SCAN_B, 0, stream>>>(degp, cnt, blockSums, off, cursor);

        fill_kernel<<<(N_EDGES + 255) / 256, 256, 0, stream>>>(src, dst, ew, dinv,
                                                               cursor, edge_s);

        wfrag_kernel<<<8, 256, 0, stream>>>(W, wfh, wfl);
        gemm_mfma_kernel<<<(N_NODES + 63) / 64, 256, 0, stream>>>(x, wfh, wfl, hbf);

        gather_kernel<<<(N_NODES + 3) / 4, 256, 0, stream>>>(off, edge_s, dinv,
                                                             hbf, b, out);
    } else {
        // ---- fallback: atomic scatter, f32 ----
        float* h    = (float*)d_ws;                 // N*D
        float* deg  = h + (size_t)N_NODES * D;      // N
        float* dv   = deg + N_NODES;                // N
        hipMemsetAsync(d_out, 0, (size_t)out_size * sizeof(float), stream);
        fb_init_kernel<<<(N_NODES + 255) / 256, 256, 0, stream>>>(deg);
        fb_deg_kernel<<<(N_EDGES + 255) / 256, 256, 0, stream>>>(dst, ew, deg);
        fb_dinv_kernel<<<(N_NODES + 255) / 256, 256, 0, stream>>>(deg, dv);
        fb_gemm_kernel<<<(N_NODES + 1) / 2, 256, 0, stream>>>(x, W, h);
        fb_scatter_kernel<<<(N_EDGES + 3) / 4, 256, 0, stream>>>(src, dst, ew, dv, h, out);
        fb_finalize_kernel<<<(N_NODES * D + 255) / 256, 256, 0, stream>>>(h, dv, b, out);
    }
}

// Round 6
// 128.945 us; speedup vs baseline: 5.0752x; 1.0018x over previous
//
#include <hip/hip_runtime.h>

#define N_NODES 50000
#define N_EDGES 600000
#define D 128
#define SCAN_B 256
#define NB ((N_NODES + SCAN_B - 1) / SCAN_B)   // 196 blocks
#define REP 8
#define FXSHIFT 44                              // count in bits [44,64), fx24 sum in [0,44)

typedef __attribute__((ext_vector_type(8))) short short8;
typedef __attribute__((ext_vector_type(4))) float f32x4;
typedef unsigned long long u64;

__device__ __forceinline__ ushort f2bf(float f) {
    unsigned u = __float_as_uint(f);
    unsigned r = (u + 0x7FFFu + ((u >> 16) & 1u)) >> 16;   // RNE
    return (ushort)r;
}
__device__ __forceinline__ float bf2f(ushort h) {
    return __uint_as_float(((unsigned)h) << 16);
}

// ---------------------------------------------------------------------------
// Fast zero for degp (the runtime fillBuffer took 43 us for 3.2 MB!).
// 16 B aligned stores, one pass.
// ---------------------------------------------------------------------------
__global__ void zero_kernel(ulonglong2* __restrict__ p, int n2) {
    int i = blockIdx.x * 256 + threadIdx.x;
    if (i < n2) p[i] = make_ulonglong2(0ull, 0ull);
}

// ---------------------------------------------------------------------------
// Per-edge: one packed u64 atomic into one of 8 replicas.
// ---------------------------------------------------------------------------
__global__ void deg_cnt_kernel(const int* __restrict__ dst,
                               const float* __restrict__ ew,
                               u64* __restrict__ degp) {
    int e = blockIdx.x * 256 + threadIdx.x;
    if (e < N_EDGES) {
        int d = dst[e];
        int r = blockIdx.x & (REP - 1);
        u64 fx = (u64)llrintf(ew[e] * 16777216.0f);
        atomicAdd(&degp[(size_t)r * N_NODES + d], (1ull << FXSHIFT) | fx);
    }
}

// ---------------------------------------------------------------------------
// scan1 (fused with dinv): replica-sum -> dinv + count; block-local exclusive
// scan; raw block sums out.
// ---------------------------------------------------------------------------
__global__ void scan1_kernel(const u64* __restrict__ degp,
                             float* __restrict__ dinv,
                             int* __restrict__ cnt,
                             int* __restrict__ blockSums) {
    __shared__ int s[SCAN_B];
    int t = threadIdx.x;
    int i = blockIdx.x * SCAN_B + t;
    int v = 0;
    if (i < N_NODES) {
        u64 fxsum = 0;
        int c = 0;
#pragma unroll
        for (int r = 0; r < REP; ++r) {
            u64 p = degp[(size_t)r * N_NODES + i];
            fxsum += p & ((1ull << FXSHIFT) - 1);
            c += (int)(p >> FXSHIFT);
        }
        float deg = 1.0f + (float)fxsum * (1.0f / 16777216.0f);
        dinv[i] = rsqrtf(deg);          // deg >= 1 always
        v = c;
    }
    s[t] = v;
    __syncthreads();
    for (int o = 1; o < SCAN_B; o <<= 1) {
        int x = (t >= o) ? s[t - o] : 0;
        __syncthreads();
        s[t] += x;
        __syncthreads();
    }
    if (i < N_NODES) cnt[i] = s[t] - v;
    if (t == SCAN_B - 1) blockSums[blockIdx.x] = s[t];
}

// off[i] + per-replica fill cursors; scan of raw blockSums folded in.
__global__ void scan3_kernel(const u64* __restrict__ degp,
                             const int* __restrict__ cnt,
                             const int* __restrict__ blockSums,
                             int* __restrict__ off,
                             int* __restrict__ cursor) {
    __shared__ int sbase;
    if (threadIdx.x == 0) {
        int s = 0;
        for (int r = 0; r < blockIdx.x; ++r) s += blockSums[r];
        sbase = s;
    }
    __syncthreads();
    int i = blockIdx.x * SCAN_B + threadIdx.x;
    if (i < N_NODES) {
        int o = cnt[i] + sbase;
        off[i] = o;
        int run = o;
#pragma unroll
        for (int r = 0; r < REP; ++r) {
            cursor[(size_t)r * N_NODES + i] = run;
            run += (int)(degp[(size_t)r * N_NODES + i] >> FXSHIFT);
        }
    }
    if (i == 0) off[N_NODES] = N_EDGES;
}

// ---------------------------------------------------------------------------
// Fill dst-sorted packed edge array: (norm_bits << 32) | src
// ---------------------------------------------------------------------------
__global__ void fill_kernel(const int* __restrict__ src, const int* __restrict__ dst,
                            const float* __restrict__ ew, const float* __restrict__ dinv,
                            int* __restrict__ cursor,
                            u64* __restrict__ edge_s) {
    int e = blockIdx.x * 256 + threadIdx.x;
    if (e >= N_EDGES) return;
    int s = src[e];
    int d = dst[e];
    int r = blockIdx.x & (REP - 1);
    int pos = atomicAdd(&cursor[(size_t)r * N_NODES + d], 1);
    float w = ew[e] * dinv[s] * dinv[d];
    edge_s[pos] = ((u64)__float_as_uint(w) << 32) | (unsigned)s;
}

// ---------------------------------------------------------------------------
// W fragment precompute (hi/lo bf16 split), MFMA B-operand lane order.
// ---------------------------------------------------------------------------
__global__ void wfrag_kernel(const float* __restrict__ W,
                             ushort* __restrict__ wfh, ushort* __restrict__ wfl) {
    int t = blockIdx.x * 256 + threadIdx.x;    // 2048 threads total
    int lane = t & 63;
    int ks   = (t >> 6) & 3;
    int ct   = t >> 8;
    int n  = ct * 16 + (lane & 15);
    int k0 = ks * 32 + (lane >> 4) * 8;
    ushort hv[8], lv[8];
#pragma unroll
    for (int j = 0; j < 8; ++j) {
        float v = W[(k0 + j) * D + n];
        ushort hh = f2bf(v);
        hv[j] = hh;
        lv[j] = f2bf(v - bf2f(hh));
    }
    size_t base = (((size_t)ct * 4 + ks) * 64 + lane) * 8;
#pragma unroll
    for (int j = 0; j < 8; ++j) { wfh[base + j] = hv[j]; wfl[base + j] = lv[j]; }
}

// ---------------------------------------------------------------------------
// h = x @ W via bf16 MFMA hi/lo split; writes h as bf16.
// ---------------------------------------------------------------------------
__global__ __launch_bounds__(256) void gemm_mfma_kernel(
        const float* __restrict__ x,
        const ushort* __restrict__ wfh, const ushort* __restrict__ wfl,
        ushort* __restrict__ hbf) {
    __shared__ __attribute__((aligned(16))) ushort xh[64 * 128];
    __shared__ __attribute__((aligned(16))) ushort xl[64 * 128];

    int t  = threadIdx.x;
    int r0 = blockIdx.x * 64;

#pragma unroll
    for (int p = 0; p < 8; ++p) {
        int row  = p * 8 + (t >> 5);
        int g    = t & 31;
        int grow = r0 + row;
        float4 v = make_float4(0.f, 0.f, 0.f, 0.f);
        if (grow < N_NODES) v = ((const float4*)(x + (size_t)grow * D))[g];
        ushort4 hi, lo;
        hi.x = f2bf(v.x); lo.x = f2bf(v.x - bf2f(hi.x));
        hi.y = f2bf(v.y); lo.y = f2bf(v.y - bf2f(hi.y));
        hi.z = f2bf(v.z); lo.z = f2bf(v.z - bf2f(hi.z));
        hi.w = f2bf(v.w); lo.w = f2bf(v.w - bf2f(hi.w));
        int bo = (row * 256 + g * 8) ^ ((row & 7) << 4);
        *(ushort4*)((char*)xh + bo) = hi;
        *(ushort4*)((char*)xl + bo) = lo;
    }
    __syncthreads();

    int w  = t >> 6;
    int l  = t & 63;
    int m  = l & 15;
    int gq = l >> 4;

    f32x4 acc[8];
#pragma unroll
    for (int ct = 0; ct < 8; ++ct) acc[ct] = (f32x4){0.f, 0.f, 0.f, 0.f};

#pragma unroll
    for (int ks = 0; ks < 4; ++ks) {
        int row = w * 16 + m;
        int bo  = (row * 256 + gq * 16 + ks * 64) ^ ((row & 7) << 4);
        short8 ah = *(const short8*)((const char*)xh + bo);
        short8 al = *(const short8*)((const char*)xl + bo);
#pragma unroll
        for (int ct = 0; ct < 8; ++ct) {
            size_t fb = (((size_t)ct * 4 + ks) * 64 + l) * 8;
            short8 bh = *(const short8*)(wfh + fb);
            short8 bl = *(const short8*)(wfl + fb);
            acc[ct] = __builtin_amdgcn_mfma_f32_16x16x32_bf16(ah, bh, acc[ct], 0, 0, 0);
            acc[ct] = __builtin_amdgcn_mfma_f32_16x16x32_bf16(al, bh, acc[ct], 0, 0, 0);
            acc[ct] = __builtin_amdgcn_mfma_f32_16x16x32_bf16(ah, bl, acc[ct], 0, 0, 0);
        }
    }

    int orow0 = r0 + w * 16 + gq * 4;
#pragma unroll
    for (int ct = 0; ct < 8; ++ct) {
#pragma unroll
        for (int r = 0; r < 4; ++r) {
            int row = orow0 + r;
            if (row < N_NODES) hbf[(size_t)row * D + ct * 16 + m] = f2bf(acc[ct][r]);
        }
    }
}

// ---------------------------------------------------------------------------
// Gather: one wave per node, split-wave (32 lanes x row half-edges each).
// ---------------------------------------------------------------------------
__global__ __launch_bounds__(256) void gather_kernel(
        const int* __restrict__ off, const u64* __restrict__ edge_s,
        const float* __restrict__ dinv,
        const ushort* __restrict__ hbf, const float* __restrict__ b,
        float* __restrict__ out) {
    int node = blockIdx.x * 4 + (threadIdx.x >> 6);
    if (node >= N_NODES) return;
    int lane = threadIdx.x & 63;
    int half = lane >> 5;       // 0 or 1
    int fl   = lane & 31;       // feature group: 4*fl .. 4*fl+3

    int begin = off[node];
    int end   = off[node + 1];
    float dd  = dinv[node];
    float sw  = dd * dd;

    // self-loop contribution on half 0 only
    ushort4 sv = ((const ushort4*)(hbf + (size_t)node * D))[fl];
    float4 acc = make_float4(0.f, 0.f, 0.f, 0.f);
    if (half == 0) {
        acc.x = bf2f(sv.x) * sw; acc.y = bf2f(sv.y) * sw;
        acc.z = bf2f(sv.z) * sw; acc.w = bf2f(sv.w) * sw;
    }

    for (int j0 = begin; j0 < end; j0 += 64) {
        int nc = end - j0;
        if (nc > 64) nc = 64;
        u64 p = 0;
        if (lane < nc) p = edge_s[j0 + lane];
        int nA   = (nc + 1) >> 1;            // half A: edges [0,nA), half B: [nA,nc)
        int base = half ? nA : 0;
        int lim  = half ? (nc - nA) : nA;
#pragma unroll 2
        for (int t = 0; t < nA; ++t) {
            u64 pe = __shfl((long long)p, base + t);
            bool valid = t < lim;
            int   ss = valid ? (int)(pe & 0xFFFFFFFFu) : 0;
            float ww = valid ? __uint_as_float((unsigned)(pe >> 32)) : 0.0f;
            ushort4 v = ((const ushort4*)(hbf + (size_t)ss * D))[fl];
            acc.x = fmaf(bf2f(v.x), ww, acc.x);
            acc.y = fmaf(bf2f(v.y), ww, acc.y);
            acc.z = fmaf(bf2f(v.z), ww, acc.z);
            acc.w = fmaf(bf2f(v.w), ww, acc.w);
        }
    }

    // combine halves
    acc.x += __shfl_xor(acc.x, 32);
    acc.y += __shfl_xor(acc.y, 32);
    acc.z += __shfl_xor(acc.z, 32);
    acc.w += __shfl_xor(acc.w, 32);

    if (half == 0) {
        float4 bb = ((const float4*)b)[fl];
        float4 o4 = make_float4(fmaxf(acc.x + bb.x, 0.f), fmaxf(acc.y + bb.y, 0.f),
                                fmaxf(acc.z + bb.z, 0.f), fmaxf(acc.w + bb.w, 0.f));
        ((float4*)(out + (size_t)node * D))[fl] = o4;
    }
}

// ---------------------------------------------------------------------------
// Fallback path (small ws): R0-style atomic scatter, f32 throughout.
// ---------------------------------------------------------------------------
__global__ void fb_init_kernel(float* __restrict__ deg) {
    int i = blockIdx.x * 256 + threadIdx.x;
    if (i < N_NODES) deg[i] = 1.0f;
}
__global__ void fb_deg_kernel(const int* __restrict__ dst, const float* __restrict__ ew,
                              float* __restrict__ deg) {
    int e = blockIdx.x * 256 + threadIdx.x;
    if (e < N_EDGES) atomicAdd(&deg[dst[e]], ew[e]);
}
__global__ void fb_dinv_kernel(const float* __restrict__ deg, float* __restrict__ dinv) {
    int i = blockIdx.x * 256 + threadIdx.x;
    if (i < N_NODES) {
        float d = deg[i];
        dinv[i] = (d > 0.0f) ? rsqrtf(d) : 0.0f;
    }
}
__global__ void fb_gemm_kernel(const float* __restrict__ x, const float* __restrict__ W,
                               float* __restrict__ h) {
    __shared__ float xs[2][D];
    int lr  = threadIdx.x >> 7;
    int col = threadIdx.x & 127;
    int row = blockIdx.x * 2 + lr;
    if (row < N_NODES) xs[lr][col] = x[(size_t)row * D + col];
    __syncthreads();
    if (row >= N_NODES) return;
    float acc = 0.0f;
#pragma unroll 8
    for (int k = 0; k < D; ++k) acc = fmaf(xs[lr][k], W[k * D + col], acc);
    h[(size_t)row * D + col] = acc;
}
__global__ void fb_scatter_kernel(const int* __restrict__ src, const int* __restrict__ dst,
                                  const float* __restrict__ ew, const float* __restrict__ dinv,
                                  const float* __restrict__ h, float* __restrict__ acc) {
    int e = blockIdx.x * 4 + (threadIdx.x >> 6);
    if (e >= N_EDGES) return;
    int lane = threadIdx.x & 63;
    int s = src[e];
    int d = dst[e];
    float w = ew[e] * dinv[s] * dinv[d];
    float2 v = ((const float2*)(h + (size_t)s * D))[lane];
    float* ap = acc + (size_t)d * D + lane * 2;
    atomicAdd(ap,     v.x * w);
    atomicAdd(ap + 1, v.y * w);
}
__global__ void fb_finalize_kernel(const float* __restrict__ h, const float* __restrict__ dinv,
                                   const float* __restrict__ b, float* __restrict__ out) {
    int i = blockIdx.x * 256 + threadIdx.x;
    if (i >= N_NODES * D) return;
    int node = i >> 7;
    int col  = i & 127;
    float di = dinv[node];
    float v = out[i] + h[i] * di * di + b[col];
    out[i] = fmaxf(v, 0.0f);
}

extern "C" void kernel_launch(void* const* d_in, const int* in_sizes, int n_in,
                              void* d_out, int out_size, void* d_ws, size_t ws_size,
                              hipStream_t stream) {
    const float* x  = (const float*)d_in[0];
    const int*   ei = (const int*)d_in[1];   // [2, E]: src row then dst row
    const float* ew = (const float*)d_in[2];
    const float* W  = (const float*)d_in[3];
    const float* b  = (const float*)d_in[4];
    float*       out = (float*)d_out;

    const int* src = ei;
    const int* dst = ei + N_EDGES;

    // ---- main-path workspace layout ----
    ushort* hbf      = (ushort*)d_ws;                          // N*D bf16   (12.8 MB)
    u64*    degp     = (u64*)(hbf + (size_t)N_NODES * D);      // REP*N u64  (3.2 MB)
    float*  dinv     = (float*)(degp + (size_t)REP * N_NODES); // N
    int*    cnt      = (int*)(dinv + N_NODES);                 // N
    int*    off      = cnt + N_NODES;                          // N+1
    int*    blockSums= off + (N_NODES + 1);                    // SCAN_B
    int*    cursor   = blockSums + SCAN_B;                     // REP*N      (1.6 MB)
    u64*    edge_s   = (u64*)(cursor + (size_t)REP * N_NODES); // E u64      (4.8 MB)
    ushort* wfh      = (ushort*)(edge_s + N_EDGES);            // 16384
    ushort* wfl      = wfh + 16384;                            // 16384
    size_t need = ((size_t)(wfl + 16384) - (size_t)d_ws);

    if (ws_size >= need) {
        // custom zero (runtime fillBuffer took 43 us for this!)
        int n2 = (REP * N_NODES) / 2;    // ulonglong2 count
        zero_kernel<<<(n2 + 255) / 256, 256, 0, stream>>>((ulonglong2*)degp, n2);

        deg_cnt_kernel<<<(N_EDGES + 255) / 256, 256, 0, stream>>>(dst, ew, degp);
        scan1_kernel<<<NB, SCAN_B, 0, stream>>>(degp, dinv, cnt, blockSums);
        scan3_kernel<<<NB, SCAN_B, 0, stream>>>(degp, cnt, blockSums, off, cursor);

        fill_kernel<<<(N_EDGES + 255) / 256, 256, 0, stream>>>(src, dst, ew, dinv,
                                                               cursor, edge_s);

        wfrag_kernel<<<8, 256, 0, stream>>>(W, wfh, wfl);
        gemm_mfma_kernel<<<(N_NODES + 63) / 64, 256, 0, stream>>>(x, wfh, wfl, hbf);

        gather_kernel<<<(N_NODES + 3) / 4, 256, 0, stream>>>(off, edge_s, dinv,
                                                             hbf, b, out);
    } else {
        // ---- fallback: atomic scatter, f32 ----
        float* h    = (float*)d_ws;                 // N*D
        float* deg  = h + (size_t)N_NODES * D;      // N
        float* dv   = deg + N_NODES;                // N
        hipMemsetAsync(d_out, 0, (size_t)out_size * sizeof(float), stream);
        fb_init_kernel<<<(N_NODES + 255) / 256, 256, 0, stream>>>(deg);
        fb_deg_kernel<<<(N_EDGES + 255) / 256, 256, 0, stream>>>(dst, ew, deg);
        fb_dinv_kernel<<<(N_NODES + 255) / 256, 256, 0, stream>>>(deg, dv);
        fb_gemm_kernel<<<(N_NODES + 1) / 2, 256, 0, stream>>>(x, W, h);
        fb_scatter_kernel<<<(N_EDGES + 3) / 4, 256, 0, stream>>>(src, dst, ew, dv, h, out);
        fb_finalize_kernel<<<(N_NODES * D + 255) / 256, 256, 0, stream>>>(h, dv, b, out);
    }
}

// Round 7
// 124.761 us; speedup vs baseline: 5.2454x; 1.0335x over previous
//
#include <hip/hip_runtime.h>

#define N_NODES 50000
#define N_EDGES 600000
#define D 128
#define SCAN_B 256
#define NB ((N_NODES + SCAN_B - 1) / SCAN_B)   // 196 blocks
#define REP 8
#define FXSHIFT 44                              // count in bits [44,64), fx24 sum in [0,44)

typedef __attribute__((ext_vector_type(8))) short short8;
typedef __attribute__((ext_vector_type(4))) float f32x4;
typedef unsigned long long u64;

__device__ __forceinline__ ushort f2bf(float f) {
    unsigned u = __float_as_uint(f);
    unsigned r = (u + 0x7FFFu + ((u >> 16) & 1u)) >> 16;   // RNE
    return (ushort)r;
}
__device__ __forceinline__ float bf2f(ushort h) {
    return __uint_as_float(((unsigned)h) << 16);
}

// ---------------------------------------------------------------------------
// Fast zero for degp. 16 B aligned stores, one pass.
// ---------------------------------------------------------------------------
__global__ void zero_kernel(ulonglong2* __restrict__ p, int n2) {
    int i = blockIdx.x * 256 + threadIdx.x;
    if (i < n2) p[i] = make_ulonglong2(0ull, 0ull);
}

// ---------------------------------------------------------------------------
// Per-edge: one packed u64 atomic into one of 8 replicas.
// ---------------------------------------------------------------------------
__global__ void deg_cnt_kernel(const int* __restrict__ dst,
                               const float* __restrict__ ew,
                               u64* __restrict__ degp) {
    int e = blockIdx.x * 256 + threadIdx.x;
    if (e < N_EDGES) {
        int d = dst[e];
        int r = blockIdx.x & (REP - 1);
        u64 fx = (u64)llrintf(ew[e] * 16777216.0f);
        atomicAdd(&degp[(size_t)r * N_NODES + d], (1ull << FXSHIFT) | fx);
    }
}

// ---------------------------------------------------------------------------
// scan1 (fused with dinv): replica-sum -> dinv + count; block-local exclusive
// scan; raw block sums out.
// ---------------------------------------------------------------------------
__global__ void scan1_kernel(const u64* __restrict__ degp,
                             float* __restrict__ dinv,
                             int* __restrict__ cnt,
                             int* __restrict__ blockSums) {
    __shared__ int s[SCAN_B];
    int t = threadIdx.x;
    int i = blockIdx.x * SCAN_B + t;
    int v = 0;
    if (i < N_NODES) {
        u64 fxsum = 0;
        int c = 0;
#pragma unroll
        for (int r = 0; r < REP; ++r) {
            u64 p = degp[(size_t)r * N_NODES + i];
            fxsum += p & ((1ull << FXSHIFT) - 1);
            c += (int)(p >> FXSHIFT);
        }
        float deg = 1.0f + (float)fxsum * (1.0f / 16777216.0f);
        dinv[i] = rsqrtf(deg);          // deg >= 1 always
        v = c;
    }
    s[t] = v;
    __syncthreads();
    for (int o = 1; o < SCAN_B; o <<= 1) {
        int x = (t >= o) ? s[t - o] : 0;
        __syncthreads();
        s[t] += x;
        __syncthreads();
    }
    if (i < N_NODES) cnt[i] = s[t] - v;
    if (t == SCAN_B - 1) blockSums[blockIdx.x] = s[t];
}

// off[i] + per-replica fill cursors; scan of raw blockSums folded in.
__global__ void scan3_kernel(const u64* __restrict__ degp,
                             const int* __restrict__ cnt,
                             const int* __restrict__ blockSums,
                             int* __restrict__ off,
                             int* __restrict__ cursor) {
    __shared__ int sbase;
    if (threadIdx.x == 0) {
        int s = 0;
        for (int r = 0; r < blockIdx.x; ++r) s += blockSums[r];
        sbase = s;
    }
    __syncthreads();
    int i = blockIdx.x * SCAN_B + threadIdx.x;
    if (i < N_NODES) {
        int o = cnt[i] + sbase;
        off[i] = o;
        int run = o;
#pragma unroll
        for (int r = 0; r < REP; ++r) {
            cursor[(size_t)r * N_NODES + i] = run;
            run += (int)(degp[(size_t)r * N_NODES + i] >> FXSHIFT);
        }
    }
    if (i == 0) off[N_NODES] = N_EDGES;
}

// ---------------------------------------------------------------------------
// Fill dst-sorted packed edge array: (norm_bits << 32) | src
// ---------------------------------------------------------------------------
__global__ void fill_kernel(const int* __restrict__ src, const int* __restrict__ dst,
                            const float* __restrict__ ew, const float* __restrict__ dinv,
                            int* __restrict__ cursor,
                            u64* __restrict__ edge_s) {
    int e = blockIdx.x * 256 + threadIdx.x;
    if (e >= N_EDGES) return;
    int s = src[e];
    int d = dst[e];
    int r = blockIdx.x & (REP - 1);
    int pos = atomicAdd(&cursor[(size_t)r * N_NODES + d], 1);
    float w = ew[e] * dinv[s] * dinv[d];
    edge_s[pos] = ((u64)__float_as_uint(w) << 32) | (unsigned)s;
}

// ---------------------------------------------------------------------------
// W fragment precompute (hi/lo bf16 split), MFMA B-operand lane order.
// ---------------------------------------------------------------------------
__global__ void wfrag_kernel(const float* __restrict__ W,
                             ushort* __restrict__ wfh, ushort* __restrict__ wfl) {
    int t = blockIdx.x * 256 + threadIdx.x;    // 2048 threads total
    int lane = t & 63;
    int ks   = (t >> 6) & 3;
    int ct   = t >> 8;
    int n  = ct * 16 + (lane & 15);
    int k0 = ks * 32 + (lane >> 4) * 8;
    ushort hv[8], lv[8];
#pragma unroll
    for (int j = 0; j < 8; ++j) {
        float v = W[(k0 + j) * D + n];
        ushort hh = f2bf(v);
        hv[j] = hh;
        lv[j] = f2bf(v - bf2f(hh));
    }
    size_t base = (((size_t)ct * 4 + ks) * 64 + lane) * 8;
#pragma unroll
    for (int j = 0; j < 8; ++j) { wfh[base + j] = hv[j]; wfl[base + j] = lv[j]; }
}

// ---------------------------------------------------------------------------
// h = x @ W via bf16 MFMA hi/lo split; writes h as bf16.
// ---------------------------------------------------------------------------
__global__ __launch_bounds__(256) void gemm_mfma_kernel(
        const float* __restrict__ x,
        const ushort* __restrict__ wfh, const ushort* __restrict__ wfl,
        ushort* __restrict__ hbf) {
    __shared__ __attribute__((aligned(16))) ushort xh[64 * 128];
    __shared__ __attribute__((aligned(16))) ushort xl[64 * 128];

    int t  = threadIdx.x;
    int r0 = blockIdx.x * 64;

#pragma unroll
    for (int p = 0; p < 8; ++p) {
        int row  = p * 8 + (t >> 5);
        int g    = t & 31;
        int grow = r0 + row;
        float4 v = make_float4(0.f, 0.f, 0.f, 0.f);
        if (grow < N_NODES) v = ((const float4*)(x + (size_t)grow * D))[g];
        ushort4 hi, lo;
        hi.x = f2bf(v.x); lo.x = f2bf(v.x - bf2f(hi.x));
        hi.y = f2bf(v.y); lo.y = f2bf(v.y - bf2f(hi.y));
        hi.z = f2bf(v.z); lo.z = f2bf(v.z - bf2f(hi.z));
        hi.w = f2bf(v.w); lo.w = f2bf(v.w - bf2f(hi.w));
        int bo = (row * 256 + g * 8) ^ ((row & 7) << 4);
        *(ushort4*)((char*)xh + bo) = hi;
        *(ushort4*)((char*)xl + bo) = lo;
    }
    __syncthreads();

    int w  = t >> 6;
    int l  = t & 63;
    int m  = l & 15;
    int gq = l >> 4;

    f32x4 acc[8];
#pragma unroll
    for (int ct = 0; ct < 8; ++ct) acc[ct] = (f32x4){0.f, 0.f, 0.f, 0.f};

#pragma unroll
    for (int ks = 0; ks < 4; ++ks) {
        int row = w * 16 + m;
        int bo  = (row * 256 + gq * 16 + ks * 64) ^ ((row & 7) << 4);
        short8 ah = *(const short8*)((const char*)xh + bo);
        short8 al = *(const short8*)((const char*)xl + bo);
#pragma unroll
        for (int ct = 0; ct < 8; ++ct) {
            size_t fb = (((size_t)ct * 4 + ks) * 64 + l) * 8;
            short8 bh = *(const short8*)(wfh + fb);
            short8 bl = *(const short8*)(wfl + fb);
            acc[ct] = __builtin_amdgcn_mfma_f32_16x16x32_bf16(ah, bh, acc[ct], 0, 0, 0);
            acc[ct] = __builtin_amdgcn_mfma_f32_16x16x32_bf16(al, bh, acc[ct], 0, 0, 0);
            acc[ct] = __builtin_amdgcn_mfma_f32_16x16x32_bf16(ah, bl, acc[ct], 0, 0, 0);
        }
    }

    int orow0 = r0 + w * 16 + gq * 4;
#pragma unroll
    for (int ct = 0; ct < 8; ++ct) {
#pragma unroll
        for (int r = 0; r < 4; ++r) {
            int row = orow0 + r;
            if (row < N_NODES) hbf[(size_t)row * D + ct * 16 + m] = f2bf(acc[ct][r]);
        }
    }
}

// ---------------------------------------------------------------------------
// Gather: one wave per node, 4-WAY SPLIT: 16 lanes cover the 128-feature row
// (short8 = 16 B/lane), groups q=0..3 process interleaved edge quarters
// (edge e -> group e&3, iter e>>2). Combine via shfl_xor(16), shfl_xor(32).
// ---------------------------------------------------------------------------
__global__ __launch_bounds__(256) void gather_kernel(
        const int* __restrict__ off, const u64* __restrict__ edge_s,
        const float* __restrict__ dinv,
        const ushort* __restrict__ hbf, const float* __restrict__ b,
        float* __restrict__ out) {
    int node = blockIdx.x * 4 + (threadIdx.x >> 6);
    if (node >= N_NODES) return;
    int lane = threadIdx.x & 63;
    int q  = lane >> 4;        // edge group 0..3
    int fl = lane & 15;        // feature block: 8*fl .. 8*fl+7

    int begin = off[node];
    int end   = off[node + 1];
    float dd  = dinv[node];
    float sw  = dd * dd;

    float acc[8] = {0.f, 0.f, 0.f, 0.f, 0.f, 0.f, 0.f, 0.f};

    // self-loop contribution on group 0 only
    short8 sv = ((const short8*)(hbf + (size_t)node * D))[fl];
    if (q == 0) {
#pragma unroll
        for (int j = 0; j < 8; ++j) acc[j] = bf2f((ushort)sv[j]) * sw;
    }

    for (int j0 = begin; j0 < end; j0 += 64) {
        int nc = end - j0;
        if (nc > 64) nc = 64;
        u64 p = 0;
        if (lane < nc) p = edge_s[j0 + lane];
        int iters = (nc + 3) >> 2;
#pragma unroll 2
        for (int t = 0; t < iters; ++t) {
            int ei = t * 4 + q;                       // <= 63 always
            u64 pe = __shfl((long long)p, ei);
            bool valid = ei < nc;
            int   ss = valid ? (int)(pe & 0xFFFFFFFFu) : 0;
            float ww = valid ? __uint_as_float((unsigned)(pe >> 32)) : 0.0f;
            short8 v = ((const short8*)(hbf + (size_t)ss * D))[fl];
#pragma unroll
            for (int j = 0; j < 8; ++j)
                acc[j] = fmaf(bf2f((ushort)v[j]), ww, acc[j]);
        }
    }

    // combine the 4 groups
#pragma unroll
    for (int j = 0; j < 8; ++j) {
        acc[j] += __shfl_xor(acc[j], 16);
        acc[j] += __shfl_xor(acc[j], 32);
    }

    if (q == 0) {
        float4 b1 = ((const float4*)b)[fl * 2];
        float4 b2 = ((const float4*)b)[fl * 2 + 1];
        float4 o1 = make_float4(fmaxf(acc[0] + b1.x, 0.f), fmaxf(acc[1] + b1.y, 0.f),
                                fmaxf(acc[2] + b1.z, 0.f), fmaxf(acc[3] + b1.w, 0.f));
        float4 o2 = make_float4(fmaxf(acc[4] + b2.x, 0.f), fmaxf(acc[5] + b2.y, 0.f),
                                fmaxf(acc[6] + b2.z, 0.f), fmaxf(acc[7] + b2.w, 0.f));
        ((float4*)(out + (size_t)node * D))[fl * 2]     = o1;
        ((float4*)(out + (size_t)node * D))[fl * 2 + 1] = o2;
    }
}

// ---------------------------------------------------------------------------
// Fallback path (small ws): R0-style atomic scatter, f32 throughout.
// ---------------------------------------------------------------------------
__global__ void fb_init_kernel(float* __restrict__ deg) {
    int i = blockIdx.x * 256 + threadIdx.x;
    if (i < N_NODES) deg[i] = 1.0f;
}
__global__ void fb_deg_kernel(const int* __restrict__ dst, const float* __restrict__ ew,
                              float* __restrict__ deg) {
    int e = blockIdx.x * 256 + threadIdx.x;
    if (e < N_EDGES) atomicAdd(&deg[dst[e]], ew[e]);
}
__global__ void fb_dinv_kernel(const float* __restrict__ deg, float* __restrict__ dinv) {
    int i = blockIdx.x * 256 + threadIdx.x;
    if (i < N_NODES) {
        float d = deg[i];
        dinv[i] = (d > 0.0f) ? rsqrtf(d) : 0.0f;
    }
}
__global__ void fb_gemm_kernel(const float* __restrict__ x, const float* __restrict__ W,
                               float* __restrict__ h) {
    __shared__ float xs[2][D];
    int lr  = threadIdx.x >> 7;
    int col = threadIdx.x & 127;
    int row = blockIdx.x * 2 + lr;
    if (row < N_NODES) xs[lr][col] = x[(size_t)row * D + col];
    __syncthreads();
    if (row >= N_NODES) return;
    float acc = 0.0f;
#pragma unroll 8
    for (int k = 0; k < D; ++k) acc = fmaf(xs[lr][k], W[k * D + col], acc);
    h[(size_t)row * D + col] = acc;
}
__global__ void fb_scatter_kernel(const int* __restrict__ src, const int* __restrict__ dst,
                                  const float* __restrict__ ew, const float* __restrict__ dinv,
                                  const float* __restrict__ h, float* __restrict__ acc) {
    int e = blockIdx.x * 4 + (threadIdx.x >> 6);
    if (e >= N_EDGES) return;
    int lane = threadIdx.x & 63;
    int s = src[e];
    int d = dst[e];
    float w = ew[e] * dinv[s] * dinv[d];
    float2 v = ((const float2*)(h + (size_t)s * D))[lane];
    float* ap = acc + (size_t)d * D + lane * 2;
    atomicAdd(ap,     v.x * w);
    atomicAdd(ap + 1, v.y * w);
}
__global__ void fb_finalize_kernel(const float* __restrict__ h, const float* __restrict__ dinv,
                                   const float* __restrict__ b, float* __restrict__ out) {
    int i = blockIdx.x * 256 + threadIdx.x;
    if (i >= N_NODES * D) return;
    int node = i >> 7;
    int col  = i & 127;
    float di = dinv[node];
    float v = out[i] + h[i] * di * di + b[col];
    out[i] = fmaxf(v, 0.0f);
}

extern "C" void kernel_launch(void* const* d_in, const int* in_sizes, int n_in,
                              void* d_out, int out_size, void* d_ws, size_t ws_size,
                              hipStream_t stream) {
    const float* x  = (const float*)d_in[0];
    const int*   ei = (const int*)d_in[1];   // [2, E]: src row then dst row
    const float* ew = (const float*)d_in[2];
    const float* W  = (const float*)d_in[3];
    const float* b  = (const float*)d_in[4];
    float*       out = (float*)d_out;

    const int* src = ei;
    const int* dst = ei + N_EDGES;

    // ---- main-path workspace layout ----
    ushort* hbf      = (ushort*)d_ws;                          // N*D bf16   (12.8 MB)
    u64*    degp     = (u64*)(hbf + (size_t)N_NODES * D);      // REP*N u64  (3.2 MB)
    float*  dinv     = (float*)(degp + (size_t)REP * N_NODES); // N
    int*    cnt      = (int*)(dinv + N_NODES);                 // N
    int*    off      = cnt + N_NODES;                          // N+1
    int*    blockSums= off + (N_NODES + 1);                    // SCAN_B
    int*    cursor   = blockSums + SCAN_B;                     // REP*N      (1.6 MB)
    u64*    edge_s   = (u64*)(cursor + (size_t)REP * N_NODES); // E u64      (4.8 MB)
    ushort* wfh      = (ushort*)(edge_s + N_EDGES);            // 16384
    ushort* wfl      = wfh + 16384;                            // 16384
    size_t need = ((size_t)(wfl + 16384) - (size_t)d_ws);

    if (ws_size >= need) {
        int n2 = (REP * N_NODES) / 2;    // ulonglong2 count
        zero_kernel<<<(n2 + 255) / 256, 256, 0, stream>>>((ulonglong2*)degp, n2);

        deg_cnt_kernel<<<(N_EDGES + 255) / 256, 256, 0, stream>>>(dst, ew, degp);
        scan1_kernel<<<NB, SCAN_B, 0, stream>>>(degp, dinv, cnt, blockSums);
        scan3_kernel<<<NB, SCAN_B, 0, stream>>>(degp, cnt, blockSums, off, cursor);

        fill_kernel<<<(N_EDGES + 255) / 256, 256, 0, stream>>>(src, dst, ew, dinv,
                                                               cursor, edge_s);

        wfrag_kernel<<<8, 256, 0, stream>>>(W, wfh, wfl);
        gemm_mfma_kernel<<<(N_NODES + 63) / 64, 256, 0, stream>>>(x, wfh, wfl, hbf);

        gather_kernel<<<(N_NODES + 3) / 4, 256, 0, stream>>>(off, edge_s, dinv,
                                                             hbf, b, out);
    } else {
        // ---- fallback: atomic scatter, f32 ----
        float* h    = (float*)d_ws;                 // N*D
        float* deg  = h + (size_t)N_NODES * D;      // N
        float* dv   = deg + N_NODES;                // N
        hipMemsetAsync(d_out, 0, (size_t)out_size * sizeof(float), stream);
        fb_init_kernel<<<(N_NODES + 255) / 256, 256, 0, stream>>>(deg);
        fb_deg_kernel<<<(N_EDGES + 255) / 256, 256, 0, stream>>>(dst, ew, deg);
        fb_dinv_kernel<<<(N_NODES + 255) / 256, 256, 0, stream>>>(deg, dv);
        fb_gemm_kernel<<<(N_NODES + 1) / 2, 256, 0, stream>>>(x, W, h);
        fb_scatter_kernel<<<(N_EDGES + 3) / 4, 256, 0, stream>>>(src, dst, ew, dv, h, out);
        fb_finalize_kernel<<<(N_NODES * D + 255) / 256, 256, 0, stream>>>(h, dv, b, out);
    }
}